// Round 5
// baseline (229.472 us; speedup 1.0000x reference)
//
#include <hip/hip_runtime.h>
#include <hip/hip_bf16.h>

// Problem constants
static constexpr int NB = 16;     // batches
static constexpr int NP = 2048;   // points per batch
static constexpr int NC = 128;    // channels
#define ALPHA_F ((float)(8.0/9.0))
#define OMA_F   ((float)(1.0 - 8.0/9.0))

typedef __attribute__((ext_vector_type(8))) short bfrag;   // 8 bf16 (4 VGPR)
typedef __attribute__((ext_vector_type(4))) float ffrag;   // 4 fp32 acc

union BU { bfrag v; uint4 u; unsigned int w[4]; };

// split two floats into packed bf16 hi pair + bf16 lo pair
__device__ inline void split2(float x, float y, unsigned& hi, unsigned& lo) {
    __hip_bfloat162 h = __float22bfloat162_rn(make_float2(x, y));
    float2 hb = __bfloat1622float2(h);
    __hip_bfloat162 l = __float22bfloat162_rn(make_float2(x - hb.x, y - hb.y));
    __builtin_memcpy(&hi, &h, 4);
    __builtin_memcpy(&lo, &l, 4);
}

__device__ inline void split1(float x, unsigned short& h, unsigned short& l) {
    __hip_bfloat16 hb = __float2bfloat16(x);
    float hf = __bfloat162float(hb);
    __hip_bfloat16 lb = __float2bfloat16(x - hf);
    __builtin_memcpy(&h, &hb, 2);
    __builtin_memcpy(&l, &lb, 2);
}

// ---------------------------------------------------------------------------
// KNN v8 (round-5): occupancy restructure at constant total work.
//  - 32 queries/block x 8 lanes/query, grid (NP/32, NB) = 1024 blocks:
//    per-lane work HALVES vs v7 (256 pass-1 dists, 8 owned groups, 32
//    pass-2 cands) while block count doubles -> same aggregate work.
//  - LDS 48.5 KB -> 32 KB: md/mi[32][65] overlaid on sp after a barrier
//    (sp dead once pass-2 done). 4 blocks/CU x 4 waves = 16 waves/CU
//    (50% cap, was 25%) -> 2x latency hiding for the dependent chains.
//  - bank geometry: pass-1 reads rotated (k+i)^q -> 8 distinct quads per
//    instruction, 8-query broadcast; pass-2 uses slot = j0 ^ (g&7) as
//    before; merge buffers stride-65.
//  - top-8-of-64 group merge: 3 bitonic shfl_xor stages (1,2,4); all 8
//    lanes converge to the same set. True-group-min semantics as v7.
// ---------------------------------------------------------------------------
__global__ __launch_bounds__(256) void knn_kernel(const float* __restrict__ xyz,
                                                  int* __restrict__ nbr) {
    __shared__ __align__(16) char shraw[32768];
    float4* sp = (float4*)shraw;                       // 2048 slots (swizzled)
    float (*md)[65] = (float(*)[65])shraw;             // overlay after pass 2
    int   (*mi)[65] = (int(*)[65])(shraw + 32 * 65 * 4);

    int tid = threadIdx.x;
    int b = blockIdx.y;
    const float* X = xyz + (size_t)b * 3 * NP;
    for (int m = tid; m < NP; m += 256) {
        float x = X[m], y = X[NP + m], z = X[2 * NP + m];
        sp[m ^ ((m >> 5) & 7)] = make_float4(x, y, z, x * x + y * y + z * z);
    }
    __syncthreads();

    int p = tid >> 3;          // query within tile (0..31)
    int q = tid & 7;           // lane within query (0..7)
    int base = blockIdx.x * 32;
    int n = base + p;
    float4 me = sp[n ^ ((n >> 5) & 7)];
    float xi = me.x, yi = me.y, zi = me.z, qi = me.w;

    // ---- pass 1: true group-min for the 8 owned groups (g = q*8 + gg)
    unsigned gd[8];
#pragma unroll
    for (int t = 0; t < 8; ++t) gd[t] = 0x7F7FFFFFu;
#pragma unroll 1
    for (int gg = 0; gg < 8; ++gg) {
        int g = q * 8 + gg;
        const float4* gp = sp + g * 32;     // swizzle permutes within block only
        float m0 = 3.4e38f, m1 = m0, m2 = m0, m3 = m0;
#pragma unroll
        for (int k = 0; k < 32; k += 4) {
            // order-invariant scan rotated by q: per instruction the 8
            // q-lanes hit 8 distinct bank quads; broadcast across queries
            float4 a0 = gp[(k + 0) ^ q];
            float4 a1 = gp[(k + 1) ^ q];
            float4 a2 = gp[(k + 2) ^ q];
            float4 a3 = gp[(k + 3) ^ q];
            m0 = fminf(m0, qi + a0.w - 2.0f * (xi * a0.x + yi * a0.y + zi * a0.z));
            m1 = fminf(m1, qi + a1.w - 2.0f * (xi * a1.x + yi * a1.y + zi * a1.z));
            m2 = fminf(m2, qi + a2.w - 2.0f * (xi * a2.x + yi * a2.y + zi * a2.z));
            m3 = fminf(m3, qi + a3.w - 2.0f * (xi * a3.x + yi * a3.y + zi * a3.z));
        }
        float gm = fmaxf(fminf(fminf(m0, m1), fminf(m2, m3)), 0.0f);
        unsigned pg; __builtin_memcpy(&pg, &gm, 4);
        pg = (pg & ~63u) | (unsigned)g;      // pack group id in low mantissa
        bool c[8];
#pragma unroll
        for (int t = 0; t < 8; ++t) c[t] = pg < gd[t];
#pragma unroll
        for (int t = 7; t >= 1; --t)
            gd[t] = c[t - 1] ? gd[t - 1] : (c[t] ? pg : gd[t]);
        gd[0] = c[0] ? pg : gd[0];
    }

    // ---- cross-lane merge: top-8 of the 8 lanes' sorted 8-lists (bitonic)
#define CEU(A, B) { unsigned _lo = (A) < (B) ? (A) : (B); \
                    unsigned _hi = (A) < (B) ? (B) : (A); (A) = _lo; (B) = _hi; }
#define SORT8(A) \
    CEU(A[0], A[4]); CEU(A[1], A[5]); CEU(A[2], A[6]); CEU(A[3], A[7]); \
    CEU(A[0], A[2]); CEU(A[1], A[3]); CEU(A[4], A[6]); CEU(A[5], A[7]); \
    CEU(A[0], A[1]); CEU(A[2], A[3]); CEU(A[4], A[5]); CEU(A[6], A[7]);
    unsigned cA[8];
#pragma unroll
    for (int i = 0; i < 8; ++i) {
        unsigned pb = (unsigned)__shfl_xor((int)gd[7 - i], 1);
        cA[i] = gd[i] < pb ? gd[i] : pb;     // 8 smallest of 16 (bitonic half)
    }
    SORT8(cA);
    unsigned dA[8];
#pragma unroll
    for (int i = 0; i < 8; ++i) {
        unsigned pb = (unsigned)__shfl_xor((int)cA[7 - i], 2);
        dA[i] = cA[i] < pb ? cA[i] : pb;     // 8 smallest of 32
    }
    SORT8(dA);
    unsigned eA[8];
#pragma unroll
    for (int i = 0; i < 8; ++i) {
        unsigned pb = (unsigned)__shfl_xor((int)dA[7 - i], 4);
        eA[i] = dA[i] < pb ? dA[i] : pb;     // 8 smallest of 64 (all lanes agree)
    }
    unsigned long long mask = 0ull;
#pragma unroll
    for (int i = 0; i < 8; ++i) mask |= (1ull << (eA[i] & 63u));

    // ---- pass 2: full insert over winning groups, ascending group order
    float bd[8]; int bi[8];
#pragma unroll
    for (int t = 0; t < 8; ++t) { bd[t] = 3.4e38f; bi[t] = 0; }
    while (mask) {
        int g = (int)__builtin_ctzll(mask);
        mask &= (mask - 1ull);
        int sw = g & 7;
        int jb = g * 32 + q;
#pragma unroll
        for (int i = 0; i < 4; ++i) {
            int j0 = jb + i * 8;
            float4 c4v = sp[j0 ^ sw];
            float inner = xi * c4v.x + yi * c4v.y + zi * c4v.z;
            float d = qi + c4v.w - 2.0f * inner;
            bool c[8];
#pragma unroll
            for (int t = 0; t < 8; ++t) c[t] = d < bd[t];
#pragma unroll
            for (int t = 7; t >= 1; --t) {
                bd[t] = c[t - 1] ? bd[t - 1] : (c[t] ? d : bd[t]);
                bi[t] = c[t - 1] ? bi[t - 1] : (c[t] ? j0 : bi[t]);
            }
            bd[0] = c[0] ? d : bd[0];
            bi[0] = c[0] ? j0 : bi[0];
        }
    }
    __syncthreads();            // sp now dead; overlay md/mi on it
#pragma unroll
    for (int t = 0; t < 8; ++t) {
        md[p][q * 8 + t] = bd[t];
        mi[p][q * 8 + t] = bi[t];
    }
    __syncthreads();

    if (tid < 32) {
        float fd[8]; int fi[8];
#pragma unroll
        for (int t = 0; t < 8; ++t) { fd[t] = 3.4e38f; fi[t] = 0; }
#pragma unroll 4
        for (int cc = 0; cc < 64; ++cc) {
            float d = md[tid][cc];
            int j = mi[tid][cc];
            bool c[8];
#pragma unroll
            for (int t = 0; t < 8; ++t) c[t] = d < fd[t];
#pragma unroll
            for (int t = 7; t >= 1; --t) {
                fd[t] = c[t - 1] ? fd[t - 1] : (c[t] ? d : fd[t]);
                fi[t] = c[t - 1] ? fi[t - 1] : (c[t] ? j : fi[t]);
            }
            fd[0] = c[0] ? d : fd[0];
            fi[0] = c[0] ? j : fi[0];
        }
        int row = b * NP + base + tid;
#pragma unroll
        for (int t = 0; t < 7; ++t) nbr[row * 7 + t] = fi[t + 1];
    }
}

// ---------------------------------------------------------------------------
// Generic batched transpose of last two dims: in (B,R,S) -> out (B,S,R)
// ---------------------------------------------------------------------------
__global__ __launch_bounds__(256) void transpose_kernel(const float* __restrict__ in,
                                                        float* __restrict__ out,
                                                        int R, int S) {
    __shared__ float t[32][33];
    int b = blockIdx.z;
    int s0 = blockIdx.x * 32, r0 = blockIdx.y * 32;
    const float* I = in + (size_t)b * R * S;
    float* O = out + (size_t)b * R * S;
#pragma unroll
    for (int i = 0; i < 4; ++i) {
        int r = r0 + threadIdx.y + i * 8;
        t[threadIdx.y + i * 8][threadIdx.x] = I[(size_t)r * S + s0 + threadIdx.x];
    }
    __syncthreads();
#pragma unroll
    for (int i = 0; i < 4; ++i) {
        int s = s0 + threadIdx.y + i * 8;
        O[(size_t)s * R + r0 + threadIdx.x] = t[threadIdx.x][threadIdx.y + i * 8];
    }
}

// ---------------------------------------------------------------------------
// Pre-split W into MFMA-frag-ordered bf16 hi/lo uint4 pairs (one-time).
// ---------------------------------------------------------------------------
__global__ __launch_bounds__(256) void prep_w_kernel(const float* __restrict__ Wc,
                                                     const float* __restrict__ Wg,
                                                     uint4* __restrict__ WP) {
    int t = blockIdx.x * 256 + threadIdx.x;
    int ncol = t & 127;
    int quad = (t >> 7) & 3;
    int s = (t >> 9) & 3;
    int mat = (t >> 11) & 1;
    int layer = t >> 12;
    const float* W = (mat ? Wg : Wc) + (size_t)layer * NC * NC + (size_t)ncol * NC + s * 32 + quad * 8;
    float4 a = *((const float4*)W);
    float4 b = *((const float4*)(W + 4));
    BU hi, lo;
    split2(a.x, a.y, hi.w[0], lo.w[0]);
    split2(a.z, a.w, hi.w[1], lo.w[1]);
    split2(b.x, b.y, hi.w[2], lo.w[2]);
    split2(b.z, b.w, hi.w[3], lo.w[3]);
    WP[t * 2] = hi.u;
    WP[t * 2 + 1] = lo.u;
}

// ---------------------------------------------------------------------------
// Fused GCN block v3 = v2 + XCD-aware block swizzle:
// blk -> (xcd = blk&7, slot = blk>>3); bb = xcd*2 + (slot>>5); tile = slot&31.
// With XCD = blockIdx%8 dispatch, each XCD owns exactly 2 batches, so the
// per-XCD L2 gather working set is 2 MB (fits 4 MB) instead of all 16 MB.
// Pure index permutation: bit-identical outputs.
// ---------------------------------------------------------------------------
template <int MODE>
__global__ __launch_bounds__(512) void gemm_fused_kernel(const float* __restrict__ Asrc,
                                                         const float* __restrict__ Y2in,
                                                         const int* __restrict__ nbr,
                                                         const uint4* __restrict__ WPc,
                                                         const uint4* __restrict__ WPg,
                                                         float* __restrict__ Zout,
                                                         float* __restrict__ Y2out) {
    __shared__ unsigned short AhT[64][136];   // 17.4 KB
    __shared__ unsigned short AlT[64][136];   // 17.4 KB
    __shared__ int s_nb[448];
    int tid = threadIdx.x;
    int wid = tid >> 6, lane = tid & 63;
    int quad = lane >> 4, l15 = lane & 15;
    int xcd = blockIdx.x & 7;
    int slot = blockIdx.x >> 3;
    int bb = xcd * 2 + (slot >> 5);           // batch
    int n0 = (slot & 31) << 6;                // tile base within batch
    size_t m0 = (size_t)bb * NP + n0;
    int ncol = wid * 16 + l15;

    // ---- W frags: pre-split, frag-ordered; 16 L2-hot b128 loads, zero VALU
    BU Bch[4], Bcl[4], Bgh[4], Bgl[4];
#pragma unroll
    for (int s = 0; s < 4; ++s) {
        int idx = ((s * 4 + quad) * 128 + ncol) * 2;
        Bch[s].u = WPc[idx];
        Bcl[s].u = WPc[idx + 1];
        Bgh[s].u = WPg[idx];
        Bgl[s].u = WPg[idx + 1];
    }

    // ---- stage A tile, splitting to bf16 planes inline
    if (MODE == 1) {
        if (tid < 448) s_nb[tid] = nbr[m0 * 7 + tid];
        __syncthreads();
        size_t bbase = (size_t)bb * NP;
#pragma unroll 1
        for (int it = 0; it < 4; ++it) {
            int f = tid + it * 512;
            int r = f >> 5, c4 = (f & 31) * 4;
            size_t row = m0 + r;
            float4 z = *((const float4*)(Asrc + row * NC + c4));
            float4 acc = *((const float4*)(Y2in + row * NC + c4));
#pragma unroll
            for (int t = 0; t < 7; ++t) {
                int j = s_nb[r * 7 + t];
                float4 v = *((const float4*)(Y2in + (bbase + (size_t)j) * NC + c4));
                acc.x += v.x; acc.y += v.y; acc.z += v.z; acc.w += v.w;
            }
            float4 a;
            a.x = OMA_F * (0.125f * acc.x) + z.x;
            a.y = OMA_F * (0.125f * acc.y) + z.y;
            a.z = OMA_F * (0.125f * acc.z) + z.z;
            a.w = OMA_F * (0.125f * acc.w) + z.w;
            unsigned h01, l01, h23, l23;
            split2(a.x, a.y, h01, l01);
            split2(a.z, a.w, h23, l23);
            *((uint2*)&AhT[r][c4]) = make_uint2(h01, h23);
            *((uint2*)&AlT[r][c4]) = make_uint2(l01, l23);
        }
    } else {
        // A[r][c] = points[b][c][n0+r]: float4 along n, split scalar, b16 writes
#pragma unroll
        for (int it = 0; it < 4; ++it) {
            int f = tid + it * 512;
            int c = f >> 4, rq = (f & 15) * 4;
            float4 v = *((const float4*)(Asrc + ((size_t)bb * NC + c) * NP + n0 + rq));
            float vv[4] = {v.x, v.y, v.z, v.w};
#pragma unroll
            for (int k = 0; k < 4; ++k) {
                unsigned short h, l;
                split1(vv[k], h, l);
                AhT[rq + k][c] = h;
                AlT[rq + k][c] = l;
            }
        }
    }
    __syncthreads();

    ffrag accC[4], accG[4];
#pragma unroll
    for (int mt = 0; mt < 4; ++mt) { accC[mt] = (ffrag)0.0f; accG[mt] = (ffrag)0.0f; }

#pragma unroll
    for (int s = 0; s < 4; ++s) {
#pragma unroll
        for (int mt = 0; mt < 4; ++mt) {
            int m = mt * 16 + l15;
            int k = s * 32 + quad * 8;
            BU ah, al, rh, rl;
            ah.u = *((const uint4*)&AhT[m][k]);
            al.u = *((const uint4*)&AlT[m][k]);
#pragma unroll
            for (int w = 0; w < 4; ++w) {
                unsigned msk = ((ah.w[w] & 0x80008000u) >> 15) * 0xFFFFu;
                rh.w[w] = ah.w[w] & ~msk;
                rl.w[w] = al.w[w] & ~msk;
            }
            accC[mt] = __builtin_amdgcn_mfma_f32_16x16x32_bf16(rh.v, Bch[s].v, accC[mt], 0, 0, 0);
            accC[mt] = __builtin_amdgcn_mfma_f32_16x16x32_bf16(rh.v, Bcl[s].v, accC[mt], 0, 0, 0);
            accC[mt] = __builtin_amdgcn_mfma_f32_16x16x32_bf16(rl.v, Bch[s].v, accC[mt], 0, 0, 0);
            accG[mt] = __builtin_amdgcn_mfma_f32_16x16x32_bf16(ah.v, Bgh[s].v, accG[mt], 0, 0, 0);
            accG[mt] = __builtin_amdgcn_mfma_f32_16x16x32_bf16(ah.v, Bgl[s].v, accG[mt], 0, 0, 0);
            accG[mt] = __builtin_amdgcn_mfma_f32_16x16x32_bf16(al.v, Bgh[s].v, accG[mt], 0, 0, 0);
        }
    }

    // ---- epilogue: col = l15, row = 4*quad + r; residual p = hi + lo
#pragma unroll
    for (int mt = 0; mt < 4; ++mt) {
        int rbase = mt * 16 + quad * 4;
#pragma unroll
        for (int r = 0; r < 4; ++r) {
            int rr = rbase + r;
            unsigned hb = ((unsigned)AhT[rr][ncol]) << 16;
            unsigned lb = ((unsigned)AlT[rr][ncol]) << 16;
            float hp, lp;
            __builtin_memcpy(&hp, &hb, 4);
            __builtin_memcpy(&lp, &lb, 4);
            float p = hp + lp;
            size_t idx = (m0 + rr) * NC + ncol;
            Zout[idx] = p + ALPHA_F * accC[mt][r];
            Y2out[idx] = accG[mt][r];
        }
    }
}

// ---------------------------------------------------------------------------
// Aggregate + XCD-aware swizzle (grid 4096, 256 blocks per batch):
// blk -> (xcd = blk&7, slot = blk>>3); bb = xcd*2 + (slot>>8); rblk = slot&255.
// ---------------------------------------------------------------------------
__global__ __launch_bounds__(256) void agg_kernel(const float* __restrict__ Z,
                                                  const float* __restrict__ Y2,
                                                  const int* __restrict__ nbr,
                                                  float* __restrict__ Pout) {
    int tid = threadIdx.x;
    int lane = tid & 31, rl = tid >> 5;
    int xcd = blockIdx.x & 7;
    int slot = blockIdx.x >> 3;
    int bb = xcd * 2 + (slot >> 8);
    int rblk = slot & 255;
    size_t row = ((size_t)bb << 11) + rblk * 8 + rl;
    const int* nb = nbr + row * 7;
    size_t off = row * NC + lane * 4;
    float4 ys = *((const float4*)(Y2 + off));
    size_t bbase = (size_t)bb * NP * NC;
#pragma unroll
    for (int t = 0; t < 7; ++t) {
        int j = nb[t];
        float4 v = *((const float4*)(Y2 + bbase + (size_t)j * NC + lane * 4));
        ys.x += v.x; ys.y += v.y; ys.z += v.z; ys.w += v.w;
    }
    float4 z = *((const float4*)(Z + off));
    float4 o;
    o.x = OMA_F * (0.125f * ys.x) + z.x;
    o.y = OMA_F * (0.125f * ys.y) + z.y;
    o.z = OMA_F * (0.125f * ys.z) + z.z;
    o.w = OMA_F * (0.125f * ys.w) + z.w;
    *((float4*)(Pout + off)) = o;
}

// ---------------------------------------------------------------------------
// Final small GEMMs: U1 = P @ Wuc^T (6), U2 = P @ Wug^T (6); U row = [U1|U2]
// ---------------------------------------------------------------------------
__global__ __launch_bounds__(256) void final_gemm_kernel(const float* __restrict__ P,
                                                         const float* __restrict__ Wuc,
                                                         const float* __restrict__ Wug,
                                                         float* __restrict__ U) {
    __shared__ float s1[6 * NC], s2[6 * NC];
    for (int m = threadIdx.x; m < 6 * NC; m += 256) { s1[m] = Wuc[m]; s2[m] = Wug[m]; }
    __syncthreads();
    size_t row = (size_t)blockIdx.x * 256 + threadIdx.x;
    const float4* prow = (const float4*)(P + row * NC);
    float a1[6] = {0, 0, 0, 0, 0, 0}, a2[6] = {0, 0, 0, 0, 0, 0};
#pragma unroll 4
    for (int c4 = 0; c4 < NC / 4; ++c4) {
        float4 p = prow[c4];
#pragma unroll
        for (int o = 0; o < 6; ++o) {
            float4 w1 = *((const float4*)&s1[o * NC + c4 * 4]);
            float4 w2 = *((const float4*)&s2[o * NC + c4 * 4]);
            a1[o] += p.x * w1.x + p.y * w1.y + p.z * w1.z + p.w * w1.w;
            a2[o] += p.x * w2.x + p.y * w2.y + p.z * w2.z + p.w * w2.w;
        }
    }
#pragma unroll
    for (int o = 0; o < 6; ++o) {
        U[row * 12 + o] = a1[o];
        U[row * 12 + 6 + o] = a2[o];
    }
}

// ---------------------------------------------------------------------------
// Final output: new_xyz
// ---------------------------------------------------------------------------
__global__ __launch_bounds__(256) void final_out_kernel(const float* __restrict__ U,
                                                        const int* __restrict__ nbr,
                                                        const float* __restrict__ xyz,
                                                        float* __restrict__ out) {
    size_t row = (size_t)blockIdx.x * 256 + threadIdx.x;
    int b = (int)(row >> 11), n = (int)(row & 2047);
    const int* nb = nbr + row * 7;
    float u1[6], u2[6];
#pragma unroll
    for (int o = 0; o < 6; ++o) { u1[o] = U[row * 12 + o]; u2[o] = U[row * 12 + 6 + o]; }
#pragma unroll
    for (int t = 0; t < 7; ++t) {
        int j = nb[t];
        const float* Uj = U + ((size_t)b * NP + j) * 12 + 6;
#pragma unroll
        for (int o = 0; o < 6; ++o) u2[o] += Uj[o];
    }
#pragma unroll
    for (int c = 0; c < 3; ++c)
#pragma unroll
        for (int s = 0; s < 2; ++s) {
            int o = c * 2 + s;
            float val = ALPHA_F * u1[o] + OMA_F * (0.125f * u2[o])
                      + xyz[(size_t)b * 3 * NP + (size_t)c * NP + n];
            out[(size_t)b * 3 * 2 * NP + (size_t)c * 2 * NP + (size_t)s * NP + n] = val;
        }
}

// ---------------------------------------------------------------------------
extern "C" void kernel_launch(void* const* d_in, const int* in_sizes, int n_in,
                              void* d_out, int out_size, void* d_ws, size_t ws_size,
                              hipStream_t stream) {
    const float* xyz    = (const float*)d_in[0];  // (16,3,2048)
    const float* points = (const float*)d_in[1];  // (16,128,2048)
    const float* Wc     = (const float*)d_in[2];  // (4,128,128)
    const float* Wg     = (const float*)d_in[3];  // (4,128,128)
    const float* Wuc    = (const float*)d_in[4];  // (6,128)
    const float* Wug    = (const float*)d_in[5];  // (6,128)
    float* out = (float*)d_out;

    char* ws = (char*)d_ws;
    size_t o = 0;
    int* nbr  = (int*)(ws + o);     o += (size_t)NB * NP * 7 * 4;
    uint4* WP = (uint4*)(ws + o);   o += (size_t)32768 * 16;           // 0.5 MB
    float* Za = (float*)(ws + o);   o += (size_t)NB * NP * NC * 4;     // 16 MB
    float* Ya = (float*)(ws + o);   o += (size_t)NB * NP * NC * 4;
    float* Zb = (float*)(ws + o);   o += (size_t)NB * NP * NC * 4;
    float* Yb = (float*)(ws + o);   o += (size_t)NB * NP * NC * 4;
    float* U  = (float*)(ws + o);   o += (size_t)NB * NP * 12 * 4;

    const int GEMM_GRID = NB * NP / 64;   // 512 tiles
    // WP slab bases: (layer*2 + mat) * 4096 uint4
    #define WPC(L) (WP + (size_t)((L) * 2 + 0) * 4096)
    #define WPG(L) (WP + (size_t)((L) * 2 + 1) * 4096)

    // 0) pre-split weights (one-time)
    prep_w_kernel<<<64, 256, 0, stream>>>(Wc, Wg, WP);
    // 1) KNN (32 queries/block x 8 lanes, 1024 blocks)
    knn_kernel<<<dim3(NP / 32, NB), 256, 0, stream>>>(xyz, nbr);
    // 2) GCN blocks — agg fused into next block's A-staging
    gemm_fused_kernel<0><<<GEMM_GRID, 512, 0, stream>>>(points, nullptr, nullptr,
        WPC(0), WPG(0), Za, Ya);
    gemm_fused_kernel<1><<<GEMM_GRID, 512, 0, stream>>>(Za, Ya, nbr,
        WPC(1), WPG(1), Zb, Yb);
    gemm_fused_kernel<1><<<GEMM_GRID, 512, 0, stream>>>(Zb, Yb, nbr,
        WPC(2), WPG(2), Za, Ya);
    gemm_fused_kernel<1><<<GEMM_GRID, 512, 0, stream>>>(Za, Ya, nbr,
        WPC(3), WPG(3), Zb, Yb);
    // 3) last agg -> P5 (reuse Za)
    float* P5 = Za;
    agg_kernel<<<dim3(NB * NP / 8), 256, 0, stream>>>(Zb, Yb, nbr, P5);
    // 4) final small GEMMs
    final_gemm_kernel<<<dim3(NB * NP / 256), 256, 0, stream>>>(P5, Wuc, Wug, U);
    // 5) new_xyz
    final_out_kernel<<<dim3(NB * NP / 256), 256, 0, stream>>>(U, nbr, xyz, out);
    // 6) pts (B,N,C) -> out2 (B,C,N)
    transpose_kernel<<<dim3(NC / 32, NP / 32, NB), dim3(32, 8), 0, stream>>>(
        P5, out + (size_t)NB * 3 * 2 * NP, NP, NC);
}

// Round 6
// 227.817 us; speedup vs baseline: 1.0073x; 1.0073x over previous
//
#include <hip/hip_runtime.h>
#include <hip/hip_bf16.h>

// Problem constants
static constexpr int NB = 16;     // batches
static constexpr int NP = 2048;   // points per batch
static constexpr int NC = 128;    // channels
#define ALPHA_F ((float)(8.0/9.0))
#define OMA_F   ((float)(1.0 - 8.0/9.0))

typedef __attribute__((ext_vector_type(8))) short bfrag;   // 8 bf16 (4 VGPR)
typedef __attribute__((ext_vector_type(4))) float ffrag;   // 4 fp32 acc

union BU { bfrag v; uint4 u; unsigned int w[4]; };

// split two floats into packed bf16 hi pair + bf16 lo pair
__device__ inline void split2(float x, float y, unsigned& hi, unsigned& lo) {
    __hip_bfloat162 h = __float22bfloat162_rn(make_float2(x, y));
    float2 hb = __bfloat1622float2(h);
    __hip_bfloat162 l = __float22bfloat162_rn(make_float2(x - hb.x, y - hb.y));
    __builtin_memcpy(&hi, &h, 4);
    __builtin_memcpy(&lo, &l, 4);
}

__device__ inline void split1(float x, unsigned short& h, unsigned short& l) {
    __hip_bfloat16 hb = __float2bfloat16(x);
    float hf = __bfloat162float(hb);
    __hip_bfloat16 lb = __float2bfloat16(x - hf);
    __builtin_memcpy(&h, &hb, 2);
    __builtin_memcpy(&l, &lb, 2);
}

// ---------------------------------------------------------------------------
// KNN v9 (round-6): v8's halved per-lane path in v7's block geometry.
// v8 post-mortem: per-CU time = blocks/CU x (stage + compute); doubling the
// grid (1024 blocks) duplicated the full-cloud staging (+2S = +10us) and ate
// the occupancy win. v9: 512 blocks (one staging pass per 64 queries, as v7)
// but 512 threads = 8 lanes/query = 8 waves/block -> 16 waves/CU cap (50%),
// with v8's per-lane program (256 pass-1 dists, 8 owned groups, 8 inserts,
// 3-stage bitonic merge, 32 pass-2 cands). LDS 33.3 KB via sp/md-mi overlay.
// Bank geometry verbatim from v8: staging swizzle m^((m>>5)&7), pass-1
// rotation (k+i)^q (8 distinct quads/instr), pass-2 slot j0^(g&7).
// ---------------------------------------------------------------------------
__global__ __launch_bounds__(512) void knn_kernel(const float* __restrict__ xyz,
                                                  int* __restrict__ nbr) {
    __shared__ __align__(16) char shraw[33280];        // max(32768, 64*65*4*2)
    float4* sp = (float4*)shraw;                       // 2048 slots (swizzled)
    float (*md)[65] = (float(*)[65])shraw;             // overlay after pass 2
    int   (*mi)[65] = (int(*)[65])(shraw + 64 * 65 * 4);

    int tid = threadIdx.x;
    int b = blockIdx.y;
    const float* X = xyz + (size_t)b * 3 * NP;
    for (int m = tid; m < NP; m += 512) {
        float x = X[m], y = X[NP + m], z = X[2 * NP + m];
        sp[m ^ ((m >> 5) & 7)] = make_float4(x, y, z, x * x + y * y + z * z);
    }
    __syncthreads();

    int p = tid >> 3;          // query within tile (0..63)
    int q = tid & 7;           // lane within query (0..7)
    int base = blockIdx.x * 64;
    int n = base + p;
    float4 me = sp[n ^ ((n >> 5) & 7)];
    float xi = me.x, yi = me.y, zi = me.z, qi = me.w;

    // ---- pass 1: true group-min for the 8 owned groups (g = q*8 + gg)
    unsigned gd[8];
#pragma unroll
    for (int t = 0; t < 8; ++t) gd[t] = 0x7F7FFFFFu;
#pragma unroll 1
    for (int gg = 0; gg < 8; ++gg) {
        int g = q * 8 + gg;
        const float4* gp = sp + g * 32;     // swizzle permutes within block only
        float m0 = 3.4e38f, m1 = m0, m2 = m0, m3 = m0;
#pragma unroll
        for (int k = 0; k < 32; k += 4) {
            // order-invariant scan rotated by q: per instruction the 8
            // q-lanes hit 8 distinct bank quads; broadcast across queries
            float4 a0 = gp[(k + 0) ^ q];
            float4 a1 = gp[(k + 1) ^ q];
            float4 a2 = gp[(k + 2) ^ q];
            float4 a3 = gp[(k + 3) ^ q];
            m0 = fminf(m0, qi + a0.w - 2.0f * (xi * a0.x + yi * a0.y + zi * a0.z));
            m1 = fminf(m1, qi + a1.w - 2.0f * (xi * a1.x + yi * a1.y + zi * a1.z));
            m2 = fminf(m2, qi + a2.w - 2.0f * (xi * a2.x + yi * a2.y + zi * a2.z));
            m3 = fminf(m3, qi + a3.w - 2.0f * (xi * a3.x + yi * a3.y + zi * a3.z));
        }
        float gm = fmaxf(fminf(fminf(m0, m1), fminf(m2, m3)), 0.0f);
        unsigned pg; __builtin_memcpy(&pg, &gm, 4);
        pg = (pg & ~63u) | (unsigned)g;      // pack group id in low mantissa
        bool c[8];
#pragma unroll
        for (int t = 0; t < 8; ++t) c[t] = pg < gd[t];
#pragma unroll
        for (int t = 7; t >= 1; --t)
            gd[t] = c[t - 1] ? gd[t - 1] : (c[t] ? pg : gd[t]);
        gd[0] = c[0] ? pg : gd[0];
    }

    // ---- cross-lane merge: top-8 of the 8 lanes' sorted 8-lists (bitonic)
#define CEU(A, B) { unsigned _lo = (A) < (B) ? (A) : (B); \
                    unsigned _hi = (A) < (B) ? (B) : (A); (A) = _lo; (B) = _hi; }
#define SORT8(A) \
    CEU(A[0], A[4]); CEU(A[1], A[5]); CEU(A[2], A[6]); CEU(A[3], A[7]); \
    CEU(A[0], A[2]); CEU(A[1], A[3]); CEU(A[4], A[6]); CEU(A[5], A[7]); \
    CEU(A[0], A[1]); CEU(A[2], A[3]); CEU(A[4], A[5]); CEU(A[6], A[7]);
    unsigned cA[8];
#pragma unroll
    for (int i = 0; i < 8; ++i) {
        unsigned pb = (unsigned)__shfl_xor((int)gd[7 - i], 1);
        cA[i] = gd[i] < pb ? gd[i] : pb;     // 8 smallest of 16 (bitonic half)
    }
    SORT8(cA);
    unsigned dA[8];
#pragma unroll
    for (int i = 0; i < 8; ++i) {
        unsigned pb = (unsigned)__shfl_xor((int)cA[7 - i], 2);
        dA[i] = cA[i] < pb ? cA[i] : pb;     // 8 smallest of 32
    }
    SORT8(dA);
    unsigned eA[8];
#pragma unroll
    for (int i = 0; i < 8; ++i) {
        unsigned pb = (unsigned)__shfl_xor((int)dA[7 - i], 4);
        eA[i] = dA[i] < pb ? dA[i] : pb;     // 8 smallest of 64 (all lanes agree)
    }
    unsigned long long mask = 0ull;
#pragma unroll
    for (int i = 0; i < 8; ++i) mask |= (1ull << (eA[i] & 63u));

    // ---- pass 2: full insert over winning groups, ascending group order
    float bd[8]; int bi[8];
#pragma unroll
    for (int t = 0; t < 8; ++t) { bd[t] = 3.4e38f; bi[t] = 0; }
    while (mask) {
        int g = (int)__builtin_ctzll(mask);
        mask &= (mask - 1ull);
        int sw = g & 7;
        int jb = g * 32 + q;
#pragma unroll
        for (int i = 0; i < 4; ++i) {
            int j0 = jb + i * 8;
            float4 c4v = sp[j0 ^ sw];
            float inner = xi * c4v.x + yi * c4v.y + zi * c4v.z;
            float d = qi + c4v.w - 2.0f * inner;
            bool c[8];
#pragma unroll
            for (int t = 0; t < 8; ++t) c[t] = d < bd[t];
#pragma unroll
            for (int t = 7; t >= 1; --t) {
                bd[t] = c[t - 1] ? bd[t - 1] : (c[t] ? d : bd[t]);
                bi[t] = c[t - 1] ? bi[t - 1] : (c[t] ? j0 : bi[t]);
            }
            bd[0] = c[0] ? d : bd[0];
            bi[0] = c[0] ? j0 : bi[0];
        }
    }
    __syncthreads();            // sp now dead; overlay md/mi on it
#pragma unroll
    for (int t = 0; t < 8; ++t) {
        md[p][q * 8 + t] = bd[t];
        mi[p][q * 8 + t] = bi[t];
    }
    __syncthreads();

    if (tid < 64) {
        float fd[8]; int fi[8];
#pragma unroll
        for (int t = 0; t < 8; ++t) { fd[t] = 3.4e38f; fi[t] = 0; }
#pragma unroll 4
        for (int cc = 0; cc < 64; ++cc) {
            float d = md[tid][cc];
            int j = mi[tid][cc];
            bool c[8];
#pragma unroll
            for (int t = 0; t < 8; ++t) c[t] = d < fd[t];
#pragma unroll
            for (int t = 7; t >= 1; --t) {
                fd[t] = c[t - 1] ? fd[t - 1] : (c[t] ? d : fd[t]);
                fi[t] = c[t - 1] ? fi[t - 1] : (c[t] ? j : fi[t]);
            }
            fd[0] = c[0] ? d : fd[0];
            fi[0] = c[0] ? j : fi[0];
        }
        int row = b * NP + base + tid;
#pragma unroll
        for (int t = 0; t < 7; ++t) nbr[row * 7 + t] = fi[t + 1];
    }
}

// ---------------------------------------------------------------------------
// Generic batched transpose of last two dims: in (B,R,S) -> out (B,S,R)
// ---------------------------------------------------------------------------
__global__ __launch_bounds__(256) void transpose_kernel(const float* __restrict__ in,
                                                        float* __restrict__ out,
                                                        int R, int S) {
    __shared__ float t[32][33];
    int b = blockIdx.z;
    int s0 = blockIdx.x * 32, r0 = blockIdx.y * 32;
    const float* I = in + (size_t)b * R * S;
    float* O = out + (size_t)b * R * S;
#pragma unroll
    for (int i = 0; i < 4; ++i) {
        int r = r0 + threadIdx.y + i * 8;
        t[threadIdx.y + i * 8][threadIdx.x] = I[(size_t)r * S + s0 + threadIdx.x];
    }
    __syncthreads();
#pragma unroll
    for (int i = 0; i < 4; ++i) {
        int s = s0 + threadIdx.y + i * 8;
        O[(size_t)s * R + r0 + threadIdx.x] = t[threadIdx.x][threadIdx.y + i * 8];
    }
}

// ---------------------------------------------------------------------------
// Pre-split W into MFMA-frag-ordered bf16 hi/lo uint4 pairs (one-time).
// ---------------------------------------------------------------------------
__global__ __launch_bounds__(256) void prep_w_kernel(const float* __restrict__ Wc,
                                                     const float* __restrict__ Wg,
                                                     uint4* __restrict__ WP) {
    int t = blockIdx.x * 256 + threadIdx.x;
    int ncol = t & 127;
    int quad = (t >> 7) & 3;
    int s = (t >> 9) & 3;
    int mat = (t >> 11) & 1;
    int layer = t >> 12;
    const float* W = (mat ? Wg : Wc) + (size_t)layer * NC * NC + (size_t)ncol * NC + s * 32 + quad * 8;
    float4 a = *((const float4*)W);
    float4 b = *((const float4*)(W + 4));
    BU hi, lo;
    split2(a.x, a.y, hi.w[0], lo.w[0]);
    split2(a.z, a.w, hi.w[1], lo.w[1]);
    split2(b.x, b.y, hi.w[2], lo.w[2]);
    split2(b.z, b.w, hi.w[3], lo.w[3]);
    WP[t * 2] = hi.u;
    WP[t * 2 + 1] = lo.u;
}

// ---------------------------------------------------------------------------
// Fused GCN block v3 = v2 + XCD-aware block swizzle:
// blk -> (xcd = blk&7, slot = blk>>3); bb = xcd*2 + (slot>>5); tile = slot&31.
// With XCD = blockIdx%8 dispatch, each XCD owns exactly 2 batches, so the
// per-XCD L2 gather working set is 2 MB (fits 4 MB) instead of all 16 MB.
// Pure index permutation: bit-identical outputs.
// ---------------------------------------------------------------------------
template <int MODE>
__global__ __launch_bounds__(512) void gemm_fused_kernel(const float* __restrict__ Asrc,
                                                         const float* __restrict__ Y2in,
                                                         const int* __restrict__ nbr,
                                                         const uint4* __restrict__ WPc,
                                                         const uint4* __restrict__ WPg,
                                                         float* __restrict__ Zout,
                                                         float* __restrict__ Y2out) {
    __shared__ unsigned short AhT[64][136];   // 17.4 KB
    __shared__ unsigned short AlT[64][136];   // 17.4 KB
    __shared__ int s_nb[448];
    int tid = threadIdx.x;
    int wid = tid >> 6, lane = tid & 63;
    int quad = lane >> 4, l15 = lane & 15;
    int xcd = blockIdx.x & 7;
    int slot = blockIdx.x >> 3;
    int bb = xcd * 2 + (slot >> 5);           // batch
    int n0 = (slot & 31) << 6;                // tile base within batch
    size_t m0 = (size_t)bb * NP + n0;
    int ncol = wid * 16 + l15;

    // ---- W frags: pre-split, frag-ordered; 16 L2-hot b128 loads, zero VALU
    BU Bch[4], Bcl[4], Bgh[4], Bgl[4];
#pragma unroll
    for (int s = 0; s < 4; ++s) {
        int idx = ((s * 4 + quad) * 128 + ncol) * 2;
        Bch[s].u = WPc[idx];
        Bcl[s].u = WPc[idx + 1];
        Bgh[s].u = WPg[idx];
        Bgl[s].u = WPg[idx + 1];
    }

    // ---- stage A tile, splitting to bf16 planes inline
    if (MODE == 1) {
        if (tid < 448) s_nb[tid] = nbr[m0 * 7 + tid];
        __syncthreads();
        size_t bbase = (size_t)bb * NP;
#pragma unroll 1
        for (int it = 0; it < 4; ++it) {
            int f = tid + it * 512;
            int r = f >> 5, c4 = (f & 31) * 4;
            size_t row = m0 + r;
            float4 z = *((const float4*)(Asrc + row * NC + c4));
            float4 acc = *((const float4*)(Y2in + row * NC + c4));
#pragma unroll
            for (int t = 0; t < 7; ++t) {
                int j = s_nb[r * 7 + t];
                float4 v = *((const float4*)(Y2in + (bbase + (size_t)j) * NC + c4));
                acc.x += v.x; acc.y += v.y; acc.z += v.z; acc.w += v.w;
            }
            float4 a;
            a.x = OMA_F * (0.125f * acc.x) + z.x;
            a.y = OMA_F * (0.125f * acc.y) + z.y;
            a.z = OMA_F * (0.125f * acc.z) + z.z;
            a.w = OMA_F * (0.125f * acc.w) + z.w;
            unsigned h01, l01, h23, l23;
            split2(a.x, a.y, h01, l01);
            split2(a.z, a.w, h23, l23);
            *((uint2*)&AhT[r][c4]) = make_uint2(h01, h23);
            *((uint2*)&AlT[r][c4]) = make_uint2(l01, l23);
        }
    } else {
        // A[r][c] = points[b][c][n0+r]: float4 along n, split scalar, b16 writes
#pragma unroll
        for (int it = 0; it < 4; ++it) {
            int f = tid + it * 512;
            int c = f >> 4, rq = (f & 15) * 4;
            float4 v = *((const float4*)(Asrc + ((size_t)bb * NC + c) * NP + n0 + rq));
            float vv[4] = {v.x, v.y, v.z, v.w};
#pragma unroll
            for (int k = 0; k < 4; ++k) {
                unsigned short h, l;
                split1(vv[k], h, l);
                AhT[rq + k][c] = h;
                AlT[rq + k][c] = l;
            }
        }
    }
    __syncthreads();

    ffrag accC[4], accG[4];
#pragma unroll
    for (int mt = 0; mt < 4; ++mt) { accC[mt] = (ffrag)0.0f; accG[mt] = (ffrag)0.0f; }

#pragma unroll
    for (int s = 0; s < 4; ++s) {
#pragma unroll
        for (int mt = 0; mt < 4; ++mt) {
            int m = mt * 16 + l15;
            int k = s * 32 + quad * 8;
            BU ah, al, rh, rl;
            ah.u = *((const uint4*)&AhT[m][k]);
            al.u = *((const uint4*)&AlT[m][k]);
#pragma unroll
            for (int w = 0; w < 4; ++w) {
                unsigned msk = ((ah.w[w] & 0x80008000u) >> 15) * 0xFFFFu;
                rh.w[w] = ah.w[w] & ~msk;
                rl.w[w] = al.w[w] & ~msk;
            }
            accC[mt] = __builtin_amdgcn_mfma_f32_16x16x32_bf16(rh.v, Bch[s].v, accC[mt], 0, 0, 0);
            accC[mt] = __builtin_amdgcn_mfma_f32_16x16x32_bf16(rh.v, Bcl[s].v, accC[mt], 0, 0, 0);
            accC[mt] = __builtin_amdgcn_mfma_f32_16x16x32_bf16(rl.v, Bch[s].v, accC[mt], 0, 0, 0);
            accG[mt] = __builtin_amdgcn_mfma_f32_16x16x32_bf16(ah.v, Bgh[s].v, accG[mt], 0, 0, 0);
            accG[mt] = __builtin_amdgcn_mfma_f32_16x16x32_bf16(ah.v, Bgl[s].v, accG[mt], 0, 0, 0);
            accG[mt] = __builtin_amdgcn_mfma_f32_16x16x32_bf16(al.v, Bgh[s].v, accG[mt], 0, 0, 0);
        }
    }

    // ---- epilogue: col = l15, row = 4*quad + r; residual p = hi + lo
#pragma unroll
    for (int mt = 0; mt < 4; ++mt) {
        int rbase = mt * 16 + quad * 4;
#pragma unroll
        for (int r = 0; r < 4; ++r) {
            int rr = rbase + r;
            unsigned hb = ((unsigned)AhT[rr][ncol]) << 16;
            unsigned lb = ((unsigned)AlT[rr][ncol]) << 16;
            float hp, lp;
            __builtin_memcpy(&hp, &hb, 4);
            __builtin_memcpy(&lp, &lb, 4);
            float p = hp + lp;
            size_t idx = (m0 + rr) * NC + ncol;
            Zout[idx] = p + ALPHA_F * accC[mt][r];
            Y2out[idx] = accG[mt][r];
        }
    }
}

// ---------------------------------------------------------------------------
// Aggregate + XCD-aware swizzle (grid 4096, 256 blocks per batch):
// blk -> (xcd = blk&7, slot = blk>>3); bb = xcd*2 + (slot>>8); rblk = slot&255.
// ---------------------------------------------------------------------------
__global__ __launch_bounds__(256) void agg_kernel(const float* __restrict__ Z,
                                                  const float* __restrict__ Y2,
                                                  const int* __restrict__ nbr,
                                                  float* __restrict__ Pout) {
    int tid = threadIdx.x;
    int lane = tid & 31, rl = tid >> 5;
    int xcd = blockIdx.x & 7;
    int slot = blockIdx.x >> 3;
    int bb = xcd * 2 + (slot >> 8);
    int rblk = slot & 255;
    size_t row = ((size_t)bb << 11) + rblk * 8 + rl;
    const int* nb = nbr + row * 7;
    size_t off = row * NC + lane * 4;
    float4 ys = *((const float4*)(Y2 + off));
    size_t bbase = (size_t)bb * NP * NC;
#pragma unroll
    for (int t = 0; t < 7; ++t) {
        int j = nb[t];
        float4 v = *((const float4*)(Y2 + bbase + (size_t)j * NC + lane * 4));
        ys.x += v.x; ys.y += v.y; ys.z += v.z; ys.w += v.w;
    }
    float4 z = *((const float4*)(Z + off));
    float4 o;
    o.x = OMA_F * (0.125f * ys.x) + z.x;
    o.y = OMA_F * (0.125f * ys.y) + z.y;
    o.z = OMA_F * (0.125f * ys.z) + z.z;
    o.w = OMA_F * (0.125f * ys.w) + z.w;
    *((float4*)(Pout + off)) = o;
}

// ---------------------------------------------------------------------------
// Final small GEMMs: U1 = P @ Wuc^T (6), U2 = P @ Wug^T (6); U row = [U1|U2]
// ---------------------------------------------------------------------------
__global__ __launch_bounds__(256) void final_gemm_kernel(const float* __restrict__ P,
                                                         const float* __restrict__ Wuc,
                                                         const float* __restrict__ Wug,
                                                         float* __restrict__ U) {
    __shared__ float s1[6 * NC], s2[6 * NC];
    for (int m = threadIdx.x; m < 6 * NC; m += 256) { s1[m] = Wuc[m]; s2[m] = Wug[m]; }
    __syncthreads();
    size_t row = (size_t)blockIdx.x * 256 + threadIdx.x;
    const float4* prow = (const float4*)(P + row * NC);
    float a1[6] = {0, 0, 0, 0, 0, 0}, a2[6] = {0, 0, 0, 0, 0, 0};
#pragma unroll 4
    for (int c4 = 0; c4 < NC / 4; ++c4) {
        float4 p = prow[c4];
#pragma unroll
        for (int o = 0; o < 6; ++o) {
            float4 w1 = *((const float4*)&s1[o * NC + c4 * 4]);
            float4 w2 = *((const float4*)&s2[o * NC + c4 * 4]);
            a1[o] += p.x * w1.x + p.y * w1.y + p.z * w1.z + p.w * w1.w;
            a2[o] += p.x * w2.x + p.y * w2.y + p.z * w2.z + p.w * w2.w;
        }
    }
#pragma unroll
    for (int o = 0; o < 6; ++o) {
        U[row * 12 + o] = a1[o];
        U[row * 12 + 6 + o] = a2[o];
    }
}

// ---------------------------------------------------------------------------
// Final output: new_xyz
// ---------------------------------------------------------------------------
__global__ __launch_bounds__(256) void final_out_kernel(const float* __restrict__ U,
                                                        const int* __restrict__ nbr,
                                                        const float* __restrict__ xyz,
                                                        float* __restrict__ out) {
    size_t row = (size_t)blockIdx.x * 256 + threadIdx.x;
    int b = (int)(row >> 11), n = (int)(row & 2047);
    const int* nb = nbr + row * 7;
    float u1[6], u2[6];
#pragma unroll
    for (int o = 0; o < 6; ++o) { u1[o] = U[row * 12 + o]; u2[o] = U[row * 12 + 6 + o]; }
#pragma unroll
    for (int t = 0; t < 7; ++t) {
        int j = nb[t];
        const float* Uj = U + ((size_t)b * NP + j) * 12 + 6;
#pragma unroll
        for (int o = 0; o < 6; ++o) u2[o] += Uj[o];
    }
#pragma unroll
    for (int c = 0; c < 3; ++c)
#pragma unroll
        for (int s = 0; s < 2; ++s) {
            int o = c * 2 + s;
            float val = ALPHA_F * u1[o] + OMA_F * (0.125f * u2[o])
                      + xyz[(size_t)b * 3 * NP + (size_t)c * NP + n];
            out[(size_t)b * 3 * 2 * NP + (size_t)c * 2 * NP + (size_t)s * NP + n] = val;
        }
}

// ---------------------------------------------------------------------------
extern "C" void kernel_launch(void* const* d_in, const int* in_sizes, int n_in,
                              void* d_out, int out_size, void* d_ws, size_t ws_size,
                              hipStream_t stream) {
    const float* xyz    = (const float*)d_in[0];  // (16,3,2048)
    const float* points = (const float*)d_in[1];  // (16,128,2048)
    const float* Wc     = (const float*)d_in[2];  // (4,128,128)
    const float* Wg     = (const float*)d_in[3];  // (4,128,128)
    const float* Wuc    = (const float*)d_in[4];  // (6,128)
    const float* Wug    = (const float*)d_in[5];  // (6,128)
    float* out = (float*)d_out;

    char* ws = (char*)d_ws;
    size_t o = 0;
    int* nbr  = (int*)(ws + o);     o += (size_t)NB * NP * 7 * 4;
    uint4* WP = (uint4*)(ws + o);   o += (size_t)32768 * 16;           // 0.5 MB
    float* Za = (float*)(ws + o);   o += (size_t)NB * NP * NC * 4;     // 16 MB
    float* Ya = (float*)(ws + o);   o += (size_t)NB * NP * NC * 4;
    float* Zb = (float*)(ws + o);   o += (size_t)NB * NP * NC * 4;
    float* Yb = (float*)(ws + o);   o += (size_t)NB * NP * NC * 4;
    float* U  = (float*)(ws + o);   o += (size_t)NB * NP * 12 * 4;

    const int GEMM_GRID = NB * NP / 64;   // 512 tiles
    // WP slab bases: (layer*2 + mat) * 4096 uint4
    #define WPC(L) (WP + (size_t)((L) * 2 + 0) * 4096)
    #define WPG(L) (WP + (size_t)((L) * 2 + 1) * 4096)

    // 0) pre-split weights (one-time)
    prep_w_kernel<<<64, 256, 0, stream>>>(Wc, Wg, WP);
    // 1) KNN (64 queries/block x 8 lanes, 512 threads, 512 blocks)
    knn_kernel<<<dim3(NP / 64, NB), 512, 0, stream>>>(xyz, nbr);
    // 2) GCN blocks — agg fused into next block's A-staging
    gemm_fused_kernel<0><<<GEMM_GRID, 512, 0, stream>>>(points, nullptr, nullptr,
        WPC(0), WPG(0), Za, Ya);
    gemm_fused_kernel<1><<<GEMM_GRID, 512, 0, stream>>>(Za, Ya, nbr,
        WPC(1), WPG(1), Zb, Yb);
    gemm_fused_kernel<1><<<GEMM_GRID, 512, 0, stream>>>(Zb, Yb, nbr,
        WPC(2), WPG(2), Za, Ya);
    gemm_fused_kernel<1><<<GEMM_GRID, 512, 0, stream>>>(Za, Ya, nbr,
        WPC(3), WPG(3), Zb, Yb);
    // 3) last agg -> P5 (reuse Za)
    float* P5 = Za;
    agg_kernel<<<dim3(NB * NP / 8), 256, 0, stream>>>(Zb, Yb, nbr, P5);
    // 4) final small GEMMs
    final_gemm_kernel<<<dim3(NB * NP / 256), 256, 0, stream>>>(P5, Wuc, Wug, U);
    // 5) new_xyz
    final_out_kernel<<<dim3(NB * NP / 256), 256, 0, stream>>>(U, nbr, xyz, out);
    // 6) pts (B,N,C) -> out2 (B,C,N)
    transpose_kernel<<<dim3(NC / 32, NP / 32, NB), dim3(32, 8), 0, stream>>>(
        P5, out + (size_t)NB * 3 * 2 * NP, NP, NC);
}

// Round 7
// 217.883 us; speedup vs baseline: 1.0532x; 1.0456x over previous
//
#include <hip/hip_runtime.h>
#include <hip/hip_bf16.h>

// Problem constants
static constexpr int NB = 16;     // batches
static constexpr int NP = 2048;   // points per batch
static constexpr int NC = 128;    // channels
#define ALPHA_F ((float)(8.0/9.0))
#define OMA_F   ((float)(1.0 - 8.0/9.0))

typedef __attribute__((ext_vector_type(8))) short bfrag;   // 8 bf16 (4 VGPR)
typedef __attribute__((ext_vector_type(4))) float ffrag;   // 4 fp32 acc

union BU { bfrag v; uint4 u; unsigned int w[4]; };

// split two floats into packed bf16 hi pair + bf16 lo pair
__device__ inline void split2(float x, float y, unsigned& hi, unsigned& lo) {
    __hip_bfloat162 h = __float22bfloat162_rn(make_float2(x, y));
    float2 hb = __bfloat1622float2(h);
    __hip_bfloat162 l = __float22bfloat162_rn(make_float2(x - hb.x, y - hb.y));
    __builtin_memcpy(&hi, &h, 4);
    __builtin_memcpy(&lo, &l, 4);
}

__device__ inline void split1(float x, unsigned short& h, unsigned short& l) {
    __hip_bfloat16 hb = __float2bfloat16(x);
    float hf = __bfloat162float(hb);
    __hip_bfloat16 lb = __float2bfloat16(x - hf);
    __builtin_memcpy(&h, &hb, 2);
    __builtin_memcpy(&l, &lb, 2);
}

// ---------------------------------------------------------------------------
// KNN v7.1 (round-7): revert to the measured-best v7 geometry (256 thr,
// 4 lanes/query, 512 blocks, ~37us, total 219.8) after the 8-lane family
// (v8/v9) measured ~45us twice. Single change vs v7: pass-1 insertion uses
// the sorted-insert min/max identity
//   new[0] = min(g[0], x); new[t] = min(g[t], max(g[t-1]_old, x))
// (15 v_min_u32/v_max_u32 per group vs ~22 cmp+cndmask, no VCC chains).
// Keys are unique (group id in low bits) -> no ties -> bit-identical result.
// ---------------------------------------------------------------------------
__global__ __launch_bounds__(256) void knn_kernel(const float* __restrict__ xyz,
                                                  int* __restrict__ nbr) {
    __shared__ float4 sp[NP];            // 32 KB (XOR-swizzled slots)
    __shared__ float  md[64][33];
    __shared__ int    mi[64][33];
    int b = blockIdx.y;
    const float* X = xyz + (size_t)b * 3 * NP;
    for (int m = threadIdx.x; m < NP; m += 256) {
        float x = X[m], y = X[NP + m], z = X[2 * NP + m];
        sp[m ^ ((m >> 5) & 7)] = make_float4(x, y, z, x * x + y * y + z * z);
    }
    __syncthreads();

    int tid = threadIdx.x;
    int p = tid >> 2;
    int q = tid & 3;
    int base = blockIdx.x * 64;
    int n = base + p;
    float4 me = sp[n ^ ((n >> 5) & 7)];
    float xi = me.x, yi = me.y, zi = me.z, qi = me.w;

    // ---- pass 1: true group-min for the 16 owned groups (g = q*16 + gg)
    unsigned gd[8];
#pragma unroll
    for (int t = 0; t < 8; ++t) gd[t] = 0x7F7FFFFFu;
#pragma unroll 1
    for (int gg = 0; gg < 16; ++gg) {
        int g = q * 16 + gg;
        const float4* gp = sp + g * 32;     // swizzle permutes within block only
        float m0 = 3.4e38f, m1 = m0, m2 = m0, m3 = m0;
#pragma unroll
        for (int k = 0; k < 32; k += 4) {
            // order-invariant scan, rotated by q so the 4 q-lanes hit
            // 4 distinct bank quads per instruction (k+i^q, i=0..3)
            float4 a0 = gp[(k + 0) ^ q];
            float4 a1 = gp[(k + 1) ^ q];
            float4 a2 = gp[(k + 2) ^ q];
            float4 a3 = gp[(k + 3) ^ q];
            m0 = fminf(m0, qi + a0.w - 2.0f * (xi * a0.x + yi * a0.y + zi * a0.z));
            m1 = fminf(m1, qi + a1.w - 2.0f * (xi * a1.x + yi * a1.y + zi * a1.z));
            m2 = fminf(m2, qi + a2.w - 2.0f * (xi * a2.x + yi * a2.y + zi * a2.z));
            m3 = fminf(m3, qi + a3.w - 2.0f * (xi * a3.x + yi * a3.y + zi * a3.z));
        }
        float gm = fmaxf(fminf(fminf(m0, m1), fminf(m2, m3)), 0.0f);
        unsigned pg; __builtin_memcpy(&pg, &gm, 4);
        pg = (pg & ~63u) | (unsigned)g;      // pack group id in low mantissa
        // sorted-insert via min/max identity (keys unique -> exact)
        unsigned prev = gd[0];
        gd[0] = gd[0] < pg ? gd[0] : pg;
#pragma unroll
        for (int t = 1; t < 8; ++t) {
            unsigned mx = prev > pg ? prev : pg;
            prev = gd[t];
            gd[t] = gd[t] < mx ? gd[t] : mx;
        }
    }

    // ---- cross-lane merge: top-8 of the 4 lanes' 4x8 sorted lists (bitonic)
#define CEU(A, B) { unsigned _lo = (A) < (B) ? (A) : (B); \
                    unsigned _hi = (A) < (B) ? (B) : (A); (A) = _lo; (B) = _hi; }
    unsigned cA[8];
#pragma unroll
    for (int i = 0; i < 8; ++i) {
        unsigned pb = (unsigned)__shfl_xor((int)gd[7 - i], 1);
        cA[i] = gd[i] < pb ? gd[i] : pb;     // 8 smallest of 16 (bitonic half)
    }
    CEU(cA[0], cA[4]); CEU(cA[1], cA[5]); CEU(cA[2], cA[6]); CEU(cA[3], cA[7]);
    CEU(cA[0], cA[2]); CEU(cA[1], cA[3]); CEU(cA[4], cA[6]); CEU(cA[5], cA[7]);
    CEU(cA[0], cA[1]); CEU(cA[2], cA[3]); CEU(cA[4], cA[5]); CEU(cA[6], cA[7]);
    unsigned dA[8];
#pragma unroll
    for (int i = 0; i < 8; ++i) {
        unsigned pb = (unsigned)__shfl_xor((int)cA[7 - i], 2);
        dA[i] = cA[i] < pb ? cA[i] : pb;     // 8 smallest of 32 (all lanes agree)
    }
    unsigned long long mask = 0ull;
#pragma unroll
    for (int i = 0; i < 8; ++i) mask |= (1ull << (dA[i] & 63u));

    // ---- pass 2: full insert over winning groups, ascending group order
    float bd[8]; int bi[8];
#pragma unroll
    for (int t = 0; t < 8; ++t) { bd[t] = 3.4e38f; bi[t] = 0; }
    while (mask) {
        int g = (int)__builtin_ctzll(mask);
        mask &= (mask - 1ull);
        int sw = g & 7;
        int jb = g * 32 + q;
#pragma unroll
        for (int i = 0; i < 8; ++i) {
            int j0 = jb + i * 4;
            float4 c4v = sp[j0 ^ sw];
            float inner = xi * c4v.x + yi * c4v.y + zi * c4v.z;
            float d = qi + c4v.w - 2.0f * inner;
            bool c[8];
#pragma unroll
            for (int t = 0; t < 8; ++t) c[t] = d < bd[t];
#pragma unroll
            for (int t = 7; t >= 1; --t) {
                bd[t] = c[t - 1] ? bd[t - 1] : (c[t] ? d : bd[t]);
                bi[t] = c[t - 1] ? bi[t - 1] : (c[t] ? j0 : bi[t]);
            }
            bd[0] = c[0] ? d : bd[0];
            bi[0] = c[0] ? j0 : bi[0];
        }
    }
#pragma unroll
    for (int t = 0; t < 8; ++t) {
        md[p][q * 8 + t] = bd[t];
        mi[p][q * 8 + t] = bi[t];
    }
    __syncthreads();

    if (tid < 64) {
        float fd[8]; int fi[8];
#pragma unroll
        for (int t = 0; t < 8; ++t) { fd[t] = 3.4e38f; fi[t] = 0; }
#pragma unroll 4
        for (int cc = 0; cc < 32; ++cc) {
            float d = md[tid][cc];
            int j = mi[tid][cc];
            bool c[8];
#pragma unroll
            for (int t = 0; t < 8; ++t) c[t] = d < fd[t];
#pragma unroll
            for (int t = 7; t >= 1; --t) {
                fd[t] = c[t - 1] ? fd[t - 1] : (c[t] ? d : fd[t]);
                fi[t] = c[t - 1] ? fi[t - 1] : (c[t] ? j : fi[t]);
            }
            fd[0] = c[0] ? d : fd[0];
            fi[0] = c[0] ? j : fi[0];
        }
        int row = b * NP + base + tid;
#pragma unroll
        for (int t = 0; t < 7; ++t) nbr[row * 7 + t] = fi[t + 1];
    }
}

// ---------------------------------------------------------------------------
// Generic batched transpose of last two dims: in (B,R,S) -> out (B,S,R)
// ---------------------------------------------------------------------------
__global__ __launch_bounds__(256) void transpose_kernel(const float* __restrict__ in,
                                                        float* __restrict__ out,
                                                        int R, int S) {
    __shared__ float t[32][33];
    int b = blockIdx.z;
    int s0 = blockIdx.x * 32, r0 = blockIdx.y * 32;
    const float* I = in + (size_t)b * R * S;
    float* O = out + (size_t)b * R * S;
#pragma unroll
    for (int i = 0; i < 4; ++i) {
        int r = r0 + threadIdx.y + i * 8;
        t[threadIdx.y + i * 8][threadIdx.x] = I[(size_t)r * S + s0 + threadIdx.x];
    }
    __syncthreads();
#pragma unroll
    for (int i = 0; i < 4; ++i) {
        int s = s0 + threadIdx.y + i * 8;
        O[(size_t)s * R + r0 + threadIdx.x] = t[threadIdx.x][threadIdx.y + i * 8];
    }
}

// ---------------------------------------------------------------------------
// Pre-split W into MFMA-frag-ordered bf16 hi/lo uint4 pairs (one-time).
// ---------------------------------------------------------------------------
__global__ __launch_bounds__(256) void prep_w_kernel(const float* __restrict__ Wc,
                                                     const float* __restrict__ Wg,
                                                     uint4* __restrict__ WP) {
    int t = blockIdx.x * 256 + threadIdx.x;
    int ncol = t & 127;
    int quad = (t >> 7) & 3;
    int s = (t >> 9) & 3;
    int mat = (t >> 11) & 1;
    int layer = t >> 12;
    const float* W = (mat ? Wg : Wc) + (size_t)layer * NC * NC + (size_t)ncol * NC + s * 32 + quad * 8;
    float4 a = *((const float4*)W);
    float4 b = *((const float4*)(W + 4));
    BU hi, lo;
    split2(a.x, a.y, hi.w[0], lo.w[0]);
    split2(a.z, a.w, hi.w[1], lo.w[1]);
    split2(b.x, b.y, hi.w[2], lo.w[2]);
    split2(b.z, b.w, hi.w[3], lo.w[3]);
    WP[t * 2] = hi.u;
    WP[t * 2 + 1] = lo.u;
}

// ---------------------------------------------------------------------------
// Fused GCN block v3 = v2 + XCD-aware block swizzle:
// blk -> (xcd = blk&7, slot = blk>>3); bb = xcd*2 + (slot>>5); tile = slot&31.
// With XCD = blockIdx%8 dispatch, each XCD owns exactly 2 batches, so the
// per-XCD L2 gather working set is 2 MB (fits 4 MB) instead of all 16 MB.
// Pure index permutation: bit-identical outputs.
// ---------------------------------------------------------------------------
template <int MODE>
__global__ __launch_bounds__(512) void gemm_fused_kernel(const float* __restrict__ Asrc,
                                                         const float* __restrict__ Y2in,
                                                         const int* __restrict__ nbr,
                                                         const uint4* __restrict__ WPc,
                                                         const uint4* __restrict__ WPg,
                                                         float* __restrict__ Zout,
                                                         float* __restrict__ Y2out) {
    __shared__ unsigned short AhT[64][136];   // 17.4 KB
    __shared__ unsigned short AlT[64][136];   // 17.4 KB
    __shared__ int s_nb[448];
    int tid = threadIdx.x;
    int wid = tid >> 6, lane = tid & 63;
    int quad = lane >> 4, l15 = lane & 15;
    int xcd = blockIdx.x & 7;
    int slot = blockIdx.x >> 3;
    int bb = xcd * 2 + (slot >> 5);           // batch
    int n0 = (slot & 31) << 6;                // tile base within batch
    size_t m0 = (size_t)bb * NP + n0;
    int ncol = wid * 16 + l15;

    // ---- W frags: pre-split, frag-ordered; 16 L2-hot b128 loads, zero VALU
    BU Bch[4], Bcl[4], Bgh[4], Bgl[4];
#pragma unroll
    for (int s = 0; s < 4; ++s) {
        int idx = ((s * 4 + quad) * 128 + ncol) * 2;
        Bch[s].u = WPc[idx];
        Bcl[s].u = WPc[idx + 1];
        Bgh[s].u = WPg[idx];
        Bgl[s].u = WPg[idx + 1];
    }

    // ---- stage A tile, splitting to bf16 planes inline
    if (MODE == 1) {
        if (tid < 448) s_nb[tid] = nbr[m0 * 7 + tid];
        __syncthreads();
        size_t bbase = (size_t)bb * NP;
#pragma unroll 1
        for (int it = 0; it < 4; ++it) {
            int f = tid + it * 512;
            int r = f >> 5, c4 = (f & 31) * 4;
            size_t row = m0 + r;
            float4 z = *((const float4*)(Asrc + row * NC + c4));
            float4 acc = *((const float4*)(Y2in + row * NC + c4));
#pragma unroll
            for (int t = 0; t < 7; ++t) {
                int j = s_nb[r * 7 + t];
                float4 v = *((const float4*)(Y2in + (bbase + (size_t)j) * NC + c4));
                acc.x += v.x; acc.y += v.y; acc.z += v.z; acc.w += v.w;
            }
            float4 a;
            a.x = OMA_F * (0.125f * acc.x) + z.x;
            a.y = OMA_F * (0.125f * acc.y) + z.y;
            a.z = OMA_F * (0.125f * acc.z) + z.z;
            a.w = OMA_F * (0.125f * acc.w) + z.w;
            unsigned h01, l01, h23, l23;
            split2(a.x, a.y, h01, l01);
            split2(a.z, a.w, h23, l23);
            *((uint2*)&AhT[r][c4]) = make_uint2(h01, h23);
            *((uint2*)&AlT[r][c4]) = make_uint2(l01, l23);
        }
    } else {
        // A[r][c] = points[b][c][n0+r]: float4 along n, split scalar, b16 writes
#pragma unroll
        for (int it = 0; it < 4; ++it) {
            int f = tid + it * 512;
            int c = f >> 4, rq = (f & 15) * 4;
            float4 v = *((const float4*)(Asrc + ((size_t)bb * NC + c) * NP + n0 + rq));
            float vv[4] = {v.x, v.y, v.z, v.w};
#pragma unroll
            for (int k = 0; k < 4; ++k) {
                unsigned short h, l;
                split1(vv[k], h, l);
                AhT[rq + k][c] = h;
                AlT[rq + k][c] = l;
            }
        }
    }
    __syncthreads();

    ffrag accC[4], accG[4];
#pragma unroll
    for (int mt = 0; mt < 4; ++mt) { accC[mt] = (ffrag)0.0f; accG[mt] = (ffrag)0.0f; }

#pragma unroll
    for (int s = 0; s < 4; ++s) {
#pragma unroll
        for (int mt = 0; mt < 4; ++mt) {
            int m = mt * 16 + l15;
            int k = s * 32 + quad * 8;
            BU ah, al, rh, rl;
            ah.u = *((const uint4*)&AhT[m][k]);
            al.u = *((const uint4*)&AlT[m][k]);
#pragma unroll
            for (int w = 0; w < 4; ++w) {
                unsigned msk = ((ah.w[w] & 0x80008000u) >> 15) * 0xFFFFu;
                rh.w[w] = ah.w[w] & ~msk;
                rl.w[w] = al.w[w] & ~msk;
            }
            accC[mt] = __builtin_amdgcn_mfma_f32_16x16x32_bf16(rh.v, Bch[s].v, accC[mt], 0, 0, 0);
            accC[mt] = __builtin_amdgcn_mfma_f32_16x16x32_bf16(rh.v, Bcl[s].v, accC[mt], 0, 0, 0);
            accC[mt] = __builtin_amdgcn_mfma_f32_16x16x32_bf16(rl.v, Bch[s].v, accC[mt], 0, 0, 0);
            accG[mt] = __builtin_amdgcn_mfma_f32_16x16x32_bf16(ah.v, Bgh[s].v, accG[mt], 0, 0, 0);
            accG[mt] = __builtin_amdgcn_mfma_f32_16x16x32_bf16(ah.v, Bgl[s].v, accG[mt], 0, 0, 0);
            accG[mt] = __builtin_amdgcn_mfma_f32_16x16x32_bf16(al.v, Bgh[s].v, accG[mt], 0, 0, 0);
        }
    }

    // ---- epilogue: col = l15, row = 4*quad + r; residual p = hi + lo
#pragma unroll
    for (int mt = 0; mt < 4; ++mt) {
        int rbase = mt * 16 + quad * 4;
#pragma unroll
        for (int r = 0; r < 4; ++r) {
            int rr = rbase + r;
            unsigned hb = ((unsigned)AhT[rr][ncol]) << 16;
            unsigned lb = ((unsigned)AlT[rr][ncol]) << 16;
            float hp, lp;
            __builtin_memcpy(&hp, &hb, 4);
            __builtin_memcpy(&lp, &lb, 4);
            float p = hp + lp;
            size_t idx = (m0 + rr) * NC + ncol;
            Zout[idx] = p + ALPHA_F * accC[mt][r];
            Y2out[idx] = accG[mt][r];
        }
    }
}

// ---------------------------------------------------------------------------
// Aggregate + XCD-aware swizzle (grid 4096, 256 blocks per batch):
// blk -> (xcd = blk&7, slot = blk>>3); bb = xcd*2 + (slot>>8); rblk = slot&255.
// ---------------------------------------------------------------------------
__global__ __launch_bounds__(256) void agg_kernel(const float* __restrict__ Z,
                                                  const float* __restrict__ Y2,
                                                  const int* __restrict__ nbr,
                                                  float* __restrict__ Pout) {
    int tid = threadIdx.x;
    int lane = tid & 31, rl = tid >> 5;
    int xcd = blockIdx.x & 7;
    int slot = blockIdx.x >> 3;
    int bb = xcd * 2 + (slot >> 8);
    int rblk = slot & 255;
    size_t row = ((size_t)bb << 11) + rblk * 8 + rl;
    const int* nb = nbr + row * 7;
    size_t off = row * NC + lane * 4;
    float4 ys = *((const float4*)(Y2 + off));
    size_t bbase = (size_t)bb * NP * NC;
#pragma unroll
    for (int t = 0; t < 7; ++t) {
        int j = nb[t];
        float4 v = *((const float4*)(Y2 + bbase + (size_t)j * NC + lane * 4));
        ys.x += v.x; ys.y += v.y; ys.z += v.z; ys.w += v.w;
    }
    float4 z = *((const float4*)(Z + off));
    float4 o;
    o.x = OMA_F * (0.125f * ys.x) + z.x;
    o.y = OMA_F * (0.125f * ys.y) + z.y;
    o.z = OMA_F * (0.125f * ys.z) + z.z;
    o.w = OMA_F * (0.125f * ys.w) + z.w;
    *((float4*)(Pout + off)) = o;
}

// ---------------------------------------------------------------------------
// Final small GEMMs: U1 = P @ Wuc^T (6), U2 = P @ Wug^T (6); U row = [U1|U2]
// ---------------------------------------------------------------------------
__global__ __launch_bounds__(256) void final_gemm_kernel(const float* __restrict__ P,
                                                         const float* __restrict__ Wuc,
                                                         const float* __restrict__ Wug,
                                                         float* __restrict__ U) {
    __shared__ float s1[6 * NC], s2[6 * NC];
    for (int m = threadIdx.x; m < 6 * NC; m += 256) { s1[m] = Wuc[m]; s2[m] = Wug[m]; }
    __syncthreads();
    size_t row = (size_t)blockIdx.x * 256 + threadIdx.x;
    const float4* prow = (const float4*)(P + row * NC);
    float a1[6] = {0, 0, 0, 0, 0, 0}, a2[6] = {0, 0, 0, 0, 0, 0};
#pragma unroll 4
    for (int c4 = 0; c4 < NC / 4; ++c4) {
        float4 p = prow[c4];
#pragma unroll
        for (int o = 0; o < 6; ++o) {
            float4 w1 = *((const float4*)&s1[o * NC + c4 * 4]);
            float4 w2 = *((const float4*)&s2[o * NC + c4 * 4]);
            a1[o] += p.x * w1.x + p.y * w1.y + p.z * w1.z + p.w * w1.w;
            a2[o] += p.x * w2.x + p.y * w2.y + p.z * w2.z + p.w * w2.w;
        }
    }
#pragma unroll
    for (int o = 0; o < 6; ++o) {
        U[row * 12 + o] = a1[o];
        U[row * 12 + 6 + o] = a2[o];
    }
}

// ---------------------------------------------------------------------------
// Final output: new_xyz
// ---------------------------------------------------------------------------
__global__ __launch_bounds__(256) void final_out_kernel(const float* __restrict__ U,
                                                        const int* __restrict__ nbr,
                                                        const float* __restrict__ xyz,
                                                        float* __restrict__ out) {
    size_t row = (size_t)blockIdx.x * 256 + threadIdx.x;
    int b = (int)(row >> 11), n = (int)(row & 2047);
    const int* nb = nbr + row * 7;
    float u1[6], u2[6];
#pragma unroll
    for (int o = 0; o < 6; ++o) { u1[o] = U[row * 12 + o]; u2[o] = U[row * 12 + 6 + o]; }
#pragma unroll
    for (int t = 0; t < 7; ++t) {
        int j = nb[t];
        const float* Uj = U + ((size_t)b * NP + j) * 12 + 6;
#pragma unroll
        for (int o = 0; o < 6; ++o) u2[o] += Uj[o];
    }
#pragma unroll
    for (int c = 0; c < 3; ++c)
#pragma unroll
        for (int s = 0; s < 2; ++s) {
            int o = c * 2 + s;
            float val = ALPHA_F * u1[o] + OMA_F * (0.125f * u2[o])
                      + xyz[(size_t)b * 3 * NP + (size_t)c * NP + n];
            out[(size_t)b * 3 * 2 * NP + (size_t)c * 2 * NP + (size_t)s * NP + n] = val;
        }
}

// ---------------------------------------------------------------------------
extern "C" void kernel_launch(void* const* d_in, const int* in_sizes, int n_in,
                              void* d_out, int out_size, void* d_ws, size_t ws_size,
                              hipStream_t stream) {
    const float* xyz    = (const float*)d_in[0];  // (16,3,2048)
    const float* points = (const float*)d_in[1];  // (16,128,2048)
    const float* Wc     = (const float*)d_in[2];  // (4,128,128)
    const float* Wg     = (const float*)d_in[3];  // (4,128,128)
    const float* Wuc    = (const float*)d_in[4];  // (6,128)
    const float* Wug    = (const float*)d_in[5];  // (6,128)
    float* out = (float*)d_out;

    char* ws = (char*)d_ws;
    size_t o = 0;
    int* nbr  = (int*)(ws + o);     o += (size_t)NB * NP * 7 * 4;
    uint4* WP = (uint4*)(ws + o);   o += (size_t)32768 * 16;           // 0.5 MB
    float* Za = (float*)(ws + o);   o += (size_t)NB * NP * NC * 4;     // 16 MB
    float* Ya = (float*)(ws + o);   o += (size_t)NB * NP * NC * 4;
    float* Zb = (float*)(ws + o);   o += (size_t)NB * NP * NC * 4;
    float* Yb = (float*)(ws + o);   o += (size_t)NB * NP * NC * 4;
    float* U  = (float*)(ws + o);   o += (size_t)NB * NP * 12 * 4;

    const int GEMM_GRID = NB * NP / 64;   // 512 tiles
    // WP slab bases: (layer*2 + mat) * 4096 uint4
    #define WPC(L) (WP + (size_t)((L) * 2 + 0) * 4096)
    #define WPG(L) (WP + (size_t)((L) * 2 + 1) * 4096)

    // 0) pre-split weights (one-time)
    prep_w_kernel<<<64, 256, 0, stream>>>(Wc, Wg, WP);
    // 1) KNN
    knn_kernel<<<dim3(NP / 64, NB), 256, 0, stream>>>(xyz, nbr);
    // 2) GCN blocks — agg fused into next block's A-staging
    gemm_fused_kernel<0><<<GEMM_GRID, 512, 0, stream>>>(points, nullptr, nullptr,
        WPC(0), WPG(0), Za, Ya);
    gemm_fused_kernel<1><<<GEMM_GRID, 512, 0, stream>>>(Za, Ya, nbr,
        WPC(1), WPG(1), Zb, Yb);
    gemm_fused_kernel<1><<<GEMM_GRID, 512, 0, stream>>>(Zb, Yb, nbr,
        WPC(2), WPG(2), Za, Ya);
    gemm_fused_kernel<1><<<GEMM_GRID, 512, 0, stream>>>(Za, Ya, nbr,
        WPC(3), WPG(3), Zb, Yb);
    // 3) last agg -> P5 (reuse Za)
    float* P5 = Za;
    agg_kernel<<<dim3(NB * NP / 8), 256, 0, stream>>>(Zb, Yb, nbr, P5);
    // 4) final small GEMMs
    final_gemm_kernel<<<dim3(NB * NP / 256), 256, 0, stream>>>(P5, Wuc, Wug, U);
    // 5) new_xyz
    final_out_kernel<<<dim3(NB * NP / 256), 256, 0, stream>>>(U, nbr, xyz, out);
    // 6) pts (B,N,C) -> out2 (B,C,N)
    transpose_kernel<<<dim3(NC / 32, NP / 32, NB), dim3(32, 8), 0, stream>>>(
        P5, out + (size_t)NB * 3 * 2 * NP, NP, NC);
}

// Round 8
// 207.986 us; speedup vs baseline: 1.1033x; 1.0476x over previous
//
#include <hip/hip_runtime.h>
#include <hip/hip_bf16.h>

// Problem constants
static constexpr int NB = 16;     // batches
static constexpr int NP = 2048;   // points per batch
static constexpr int NC = 128;    // channels
#define ALPHA_F ((float)(8.0/9.0))
#define OMA_F   ((float)(1.0 - 8.0/9.0))

typedef __attribute__((ext_vector_type(8))) short bfrag;   // 8 bf16 (4 VGPR)
typedef __attribute__((ext_vector_type(4))) float ffrag;   // 4 fp32 acc

union BU { bfrag v; uint4 u; unsigned int w[4]; };

// split two floats into packed bf16 hi pair + bf16 lo pair
__device__ inline void split2(float x, float y, unsigned& hi, unsigned& lo) {
    __hip_bfloat162 h = __float22bfloat162_rn(make_float2(x, y));
    float2 hb = __bfloat1622float2(h);
    __hip_bfloat162 l = __float22bfloat162_rn(make_float2(x - hb.x, y - hb.y));
    __builtin_memcpy(&hi, &h, 4);
    __builtin_memcpy(&lo, &l, 4);
}

__device__ inline void split1(float x, unsigned short& h, unsigned short& l) {
    __hip_bfloat16 hb = __float2bfloat16(x);
    float hf = __bfloat162float(hb);
    __hip_bfloat16 lb = __float2bfloat16(x - hf);
    __builtin_memcpy(&h, &hb, 2);
    __builtin_memcpy(&l, &lb, 2);
}

// ---------------------------------------------------------------------------
// KNN v7.1 (unchanged from round-7: measured best, ~35us).
// ---------------------------------------------------------------------------
__global__ __launch_bounds__(256) void knn_kernel(const float* __restrict__ xyz,
                                                  int* __restrict__ nbr) {
    __shared__ float4 sp[NP];            // 32 KB (XOR-swizzled slots)
    __shared__ float  md[64][33];
    __shared__ int    mi[64][33];
    int b = blockIdx.y;
    const float* X = xyz + (size_t)b * 3 * NP;
    for (int m = threadIdx.x; m < NP; m += 256) {
        float x = X[m], y = X[NP + m], z = X[2 * NP + m];
        sp[m ^ ((m >> 5) & 7)] = make_float4(x, y, z, x * x + y * y + z * z);
    }
    __syncthreads();

    int tid = threadIdx.x;
    int p = tid >> 2;
    int q = tid & 3;
    int base = blockIdx.x * 64;
    int n = base + p;
    float4 me = sp[n ^ ((n >> 5) & 7)];
    float xi = me.x, yi = me.y, zi = me.z, qi = me.w;

    // ---- pass 1: true group-min for the 16 owned groups (g = q*16 + gg)
    unsigned gd[8];
#pragma unroll
    for (int t = 0; t < 8; ++t) gd[t] = 0x7F7FFFFFu;
#pragma unroll 1
    for (int gg = 0; gg < 16; ++gg) {
        int g = q * 16 + gg;
        const float4* gp = sp + g * 32;     // swizzle permutes within block only
        float m0 = 3.4e38f, m1 = m0, m2 = m0, m3 = m0;
#pragma unroll
        for (int k = 0; k < 32; k += 4) {
            // order-invariant scan, rotated by q so the 4 q-lanes hit
            // 4 distinct bank quads per instruction (k+i^q, i=0..3)
            float4 a0 = gp[(k + 0) ^ q];
            float4 a1 = gp[(k + 1) ^ q];
            float4 a2 = gp[(k + 2) ^ q];
            float4 a3 = gp[(k + 3) ^ q];
            m0 = fminf(m0, qi + a0.w - 2.0f * (xi * a0.x + yi * a0.y + zi * a0.z));
            m1 = fminf(m1, qi + a1.w - 2.0f * (xi * a1.x + yi * a1.y + zi * a1.z));
            m2 = fminf(m2, qi + a2.w - 2.0f * (xi * a2.x + yi * a2.y + zi * a2.z));
            m3 = fminf(m3, qi + a3.w - 2.0f * (xi * a3.x + yi * a3.y + zi * a3.z));
        }
        float gm = fmaxf(fminf(fminf(m0, m1), fminf(m2, m3)), 0.0f);
        unsigned pg; __builtin_memcpy(&pg, &gm, 4);
        pg = (pg & ~63u) | (unsigned)g;      // pack group id in low mantissa
        // sorted-insert via min/max identity (keys unique -> exact)
        unsigned prev = gd[0];
        gd[0] = gd[0] < pg ? gd[0] : pg;
#pragma unroll
        for (int t = 1; t < 8; ++t) {
            unsigned mx = prev > pg ? prev : pg;
            prev = gd[t];
            gd[t] = gd[t] < mx ? gd[t] : mx;
        }
    }

    // ---- cross-lane merge: top-8 of the 4 lanes' 4x8 sorted lists (bitonic)
#define CEU(A, B) { unsigned _lo = (A) < (B) ? (A) : (B); \
                    unsigned _hi = (A) < (B) ? (B) : (A); (A) = _lo; (B) = _hi; }
    unsigned cA[8];
#pragma unroll
    for (int i = 0; i < 8; ++i) {
        unsigned pb = (unsigned)__shfl_xor((int)gd[7 - i], 1);
        cA[i] = gd[i] < pb ? gd[i] : pb;     // 8 smallest of 16 (bitonic half)
    }
    CEU(cA[0], cA[4]); CEU(cA[1], cA[5]); CEU(cA[2], cA[6]); CEU(cA[3], cA[7]);
    CEU(cA[0], cA[2]); CEU(cA[1], cA[3]); CEU(cA[4], cA[6]); CEU(cA[5], cA[7]);
    CEU(cA[0], cA[1]); CEU(cA[2], cA[3]); CEU(cA[4], cA[5]); CEU(cA[6], cA[7]);
    unsigned dA[8];
#pragma unroll
    for (int i = 0; i < 8; ++i) {
        unsigned pb = (unsigned)__shfl_xor((int)cA[7 - i], 2);
        dA[i] = cA[i] < pb ? cA[i] : pb;     // 8 smallest of 32 (all lanes agree)
    }
    unsigned long long mask = 0ull;
#pragma unroll
    for (int i = 0; i < 8; ++i) mask |= (1ull << (dA[i] & 63u));

    // ---- pass 2: full insert over winning groups, ascending group order
    float bd[8]; int bi[8];
#pragma unroll
    for (int t = 0; t < 8; ++t) { bd[t] = 3.4e38f; bi[t] = 0; }
    while (mask) {
        int g = (int)__builtin_ctzll(mask);
        mask &= (mask - 1ull);
        int sw = g & 7;
        int jb = g * 32 + q;
#pragma unroll
        for (int i = 0; i < 8; ++i) {
            int j0 = jb + i * 4;
            float4 c4v = sp[j0 ^ sw];
            float inner = xi * c4v.x + yi * c4v.y + zi * c4v.z;
            float d = qi + c4v.w - 2.0f * inner;
            bool c[8];
#pragma unroll
            for (int t = 0; t < 8; ++t) c[t] = d < bd[t];
#pragma unroll
            for (int t = 7; t >= 1; --t) {
                bd[t] = c[t - 1] ? bd[t - 1] : (c[t] ? d : bd[t]);
                bi[t] = c[t - 1] ? bi[t - 1] : (c[t] ? j0 : bi[t]);
            }
            bd[0] = c[0] ? d : bd[0];
            bi[0] = c[0] ? j0 : bi[0];
        }
    }
#pragma unroll
    for (int t = 0; t < 8; ++t) {
        md[p][q * 8 + t] = bd[t];
        mi[p][q * 8 + t] = bi[t];
    }
    __syncthreads();

    if (tid < 64) {
        float fd[8]; int fi[8];
#pragma unroll
        for (int t = 0; t < 8; ++t) { fd[t] = 3.4e38f; fi[t] = 0; }
#pragma unroll 4
        for (int cc = 0; cc < 32; ++cc) {
            float d = md[tid][cc];
            int j = mi[tid][cc];
            bool c[8];
#pragma unroll
            for (int t = 0; t < 8; ++t) c[t] = d < fd[t];
#pragma unroll
            for (int t = 7; t >= 1; --t) {
                fd[t] = c[t - 1] ? fd[t - 1] : (c[t] ? d : fd[t]);
                fi[t] = c[t - 1] ? fi[t - 1] : (c[t] ? j : fi[t]);
            }
            fd[0] = c[0] ? d : fd[0];
            fi[0] = c[0] ? j : fi[0];
        }
        int row = b * NP + base + tid;
#pragma unroll
        for (int t = 0; t < 7; ++t) nbr[row * 7 + t] = fi[t + 1];
    }
}

// ---------------------------------------------------------------------------
// Pre-split W into MFMA-frag-ordered bf16 hi/lo uint4 pairs (one-time).
// ---------------------------------------------------------------------------
__global__ __launch_bounds__(256) void prep_w_kernel(const float* __restrict__ Wc,
                                                     const float* __restrict__ Wg,
                                                     uint4* __restrict__ WP) {
    int t = blockIdx.x * 256 + threadIdx.x;
    int ncol = t & 127;
    int quad = (t >> 7) & 3;
    int s = (t >> 9) & 3;
    int mat = (t >> 11) & 1;
    int layer = t >> 12;
    const float* W = (mat ? Wg : Wc) + (size_t)layer * NC * NC + (size_t)ncol * NC + s * 32 + quad * 8;
    float4 a = *((const float4*)W);
    float4 b = *((const float4*)(W + 4));
    BU hi, lo;
    split2(a.x, a.y, hi.w[0], lo.w[0]);
    split2(a.z, a.w, hi.w[1], lo.w[1]);
    split2(b.x, b.y, hi.w[2], lo.w[2]);
    split2(b.z, b.w, hi.w[3], lo.w[3]);
    WP[t * 2] = hi.u;
    WP[t * 2 + 1] = lo.u;
}

// ---------------------------------------------------------------------------
// Fused GCN block (unchanged): XCD-aware swizzle, hi/lo bf16 split MFMA.
// ---------------------------------------------------------------------------
template <int MODE>
__global__ __launch_bounds__(512) void gemm_fused_kernel(const float* __restrict__ Asrc,
                                                         const float* __restrict__ Y2in,
                                                         const int* __restrict__ nbr,
                                                         const uint4* __restrict__ WPc,
                                                         const uint4* __restrict__ WPg,
                                                         float* __restrict__ Zout,
                                                         float* __restrict__ Y2out) {
    __shared__ unsigned short AhT[64][136];   // 17.4 KB
    __shared__ unsigned short AlT[64][136];   // 17.4 KB
    __shared__ int s_nb[448];
    int tid = threadIdx.x;
    int wid = tid >> 6, lane = tid & 63;
    int quad = lane >> 4, l15 = lane & 15;
    int xcd = blockIdx.x & 7;
    int slot = blockIdx.x >> 3;
    int bb = xcd * 2 + (slot >> 5);           // batch
    int n0 = (slot & 31) << 6;                // tile base within batch
    size_t m0 = (size_t)bb * NP + n0;
    int ncol = wid * 16 + l15;

    // ---- W frags: pre-split, frag-ordered; 16 L2-hot b128 loads, zero VALU
    BU Bch[4], Bcl[4], Bgh[4], Bgl[4];
#pragma unroll
    for (int s = 0; s < 4; ++s) {
        int idx = ((s * 4 + quad) * 128 + ncol) * 2;
        Bch[s].u = WPc[idx];
        Bcl[s].u = WPc[idx + 1];
        Bgh[s].u = WPg[idx];
        Bgl[s].u = WPg[idx + 1];
    }

    // ---- stage A tile, splitting to bf16 planes inline
    if (MODE == 1) {
        if (tid < 448) s_nb[tid] = nbr[m0 * 7 + tid];
        __syncthreads();
        size_t bbase = (size_t)bb * NP;
#pragma unroll 1
        for (int it = 0; it < 4; ++it) {
            int f = tid + it * 512;
            int r = f >> 5, c4 = (f & 31) * 4;
            size_t row = m0 + r;
            float4 z = *((const float4*)(Asrc + row * NC + c4));
            float4 acc = *((const float4*)(Y2in + row * NC + c4));
#pragma unroll
            for (int t = 0; t < 7; ++t) {
                int j = s_nb[r * 7 + t];
                float4 v = *((const float4*)(Y2in + (bbase + (size_t)j) * NC + c4));
                acc.x += v.x; acc.y += v.y; acc.z += v.z; acc.w += v.w;
            }
            float4 a;
            a.x = OMA_F * (0.125f * acc.x) + z.x;
            a.y = OMA_F * (0.125f * acc.y) + z.y;
            a.z = OMA_F * (0.125f * acc.z) + z.z;
            a.w = OMA_F * (0.125f * acc.w) + z.w;
            unsigned h01, l01, h23, l23;
            split2(a.x, a.y, h01, l01);
            split2(a.z, a.w, h23, l23);
            *((uint2*)&AhT[r][c4]) = make_uint2(h01, h23);
            *((uint2*)&AlT[r][c4]) = make_uint2(l01, l23);
        }
    } else {
        // A[r][c] = points[b][c][n0+r]: float4 along n, split scalar, b16 writes
#pragma unroll
        for (int it = 0; it < 4; ++it) {
            int f = tid + it * 512;
            int c = f >> 4, rq = (f & 15) * 4;
            float4 v = *((const float4*)(Asrc + ((size_t)bb * NC + c) * NP + n0 + rq));
            float vv[4] = {v.x, v.y, v.z, v.w};
#pragma unroll
            for (int k = 0; k < 4; ++k) {
                unsigned short h, l;
                split1(vv[k], h, l);
                AhT[rq + k][c] = h;
                AlT[rq + k][c] = l;
            }
        }
    }
    __syncthreads();

    ffrag accC[4], accG[4];
#pragma unroll
    for (int mt = 0; mt < 4; ++mt) { accC[mt] = (ffrag)0.0f; accG[mt] = (ffrag)0.0f; }

#pragma unroll
    for (int s = 0; s < 4; ++s) {
#pragma unroll
        for (int mt = 0; mt < 4; ++mt) {
            int m = mt * 16 + l15;
            int k = s * 32 + quad * 8;
            BU ah, al, rh, rl;
            ah.u = *((const uint4*)&AhT[m][k]);
            al.u = *((const uint4*)&AlT[m][k]);
#pragma unroll
            for (int w = 0; w < 4; ++w) {
                unsigned msk = ((ah.w[w] & 0x80008000u) >> 15) * 0xFFFFu;
                rh.w[w] = ah.w[w] & ~msk;
                rl.w[w] = al.w[w] & ~msk;
            }
            accC[mt] = __builtin_amdgcn_mfma_f32_16x16x32_bf16(rh.v, Bch[s].v, accC[mt], 0, 0, 0);
            accC[mt] = __builtin_amdgcn_mfma_f32_16x16x32_bf16(rh.v, Bcl[s].v, accC[mt], 0, 0, 0);
            accC[mt] = __builtin_amdgcn_mfma_f32_16x16x32_bf16(rl.v, Bch[s].v, accC[mt], 0, 0, 0);
            accG[mt] = __builtin_amdgcn_mfma_f32_16x16x32_bf16(ah.v, Bgh[s].v, accG[mt], 0, 0, 0);
            accG[mt] = __builtin_amdgcn_mfma_f32_16x16x32_bf16(ah.v, Bgl[s].v, accG[mt], 0, 0, 0);
            accG[mt] = __builtin_amdgcn_mfma_f32_16x16x32_bf16(al.v, Bgh[s].v, accG[mt], 0, 0, 0);
        }
    }

    // ---- epilogue: col = l15, row = 4*quad + r; residual p = hi + lo
#pragma unroll
    for (int mt = 0; mt < 4; ++mt) {
        int rbase = mt * 16 + quad * 4;
#pragma unroll
        for (int r = 0; r < 4; ++r) {
            int rr = rbase + r;
            unsigned hb = ((unsigned)AhT[rr][ncol]) << 16;
            unsigned lb = ((unsigned)AlT[rr][ncol]) << 16;
            float hp, lp;
            __builtin_memcpy(&hp, &hb, 4);
            __builtin_memcpy(&lp, &lb, 4);
            float p = hp + lp;
            size_t idx = (m0 + rr) * NC + ncol;
            Zout[idx] = p + ALPHA_F * accC[mt][r];
            Y2out[idx] = accG[mt][r];
        }
    }
}

// ---------------------------------------------------------------------------
// agg2 (round-8): fused tail = agg + final_gemm + transpose.
// Per block: 8 rows. Computes P row values o (as old agg), then:
//  (a) U = [P@Wuc^T | P@Wug^T] via per-lane partials (one c4 chunk each) +
//      5-stage shfl_xor butterfly over the 32-lane half-wave; lane 0 of each
//      half writes the row's 12 floats (3x dwordx4, 48B-aligned).
//  (b) stages the 8x128 P tile in LDS sm[8][132] and writes out2 (B,C,N)
//      directly: thread (c=t>>1, h=t&1) reads sm[4h+i][c] (2 lanes/bank =
//      free) and writes float4 at out2[b][c][n0+4h].
// Eliminates P5, the final_gemm 16MB re-read, and the transpose 32MB pass.
// Tree-sum U vs sequential: rounding-order change only.
// ---------------------------------------------------------------------------
__global__ __launch_bounds__(256) void agg2_kernel(const float* __restrict__ Z,
                                                   const float* __restrict__ Y2,
                                                   const int* __restrict__ nbr,
                                                   const float* __restrict__ Wuc,
                                                   const float* __restrict__ Wug,
                                                   float* __restrict__ U,
                                                   float* __restrict__ out2) {
    __shared__ float s1[6 * NC], s2[6 * NC];   // 6 KB weights
    __shared__ float sm[8][132];               // 4.2 KB P tile (padded)
    int tid = threadIdx.x;
    int lane = tid & 31, rl = tid >> 5;
    for (int m = tid; m < 6 * NC; m += 256) { s1[m] = Wuc[m]; s2[m] = Wug[m]; }

    int xcd = blockIdx.x & 7;
    int slot = blockIdx.x >> 3;
    int bb = xcd * 2 + (slot >> 8);
    int rblk = slot & 255;
    int n0 = rblk * 8;
    size_t row = ((size_t)bb << 11) + n0 + rl;
    const int* nb = nbr + row * 7;
    size_t off = row * NC + lane * 4;
    float4 ys = *((const float4*)(Y2 + off));
    size_t bbase = (size_t)bb * NP * NC;
#pragma unroll
    for (int t = 0; t < 7; ++t) {
        int j = nb[t];
        float4 v = *((const float4*)(Y2 + bbase + (size_t)j * NC + lane * 4));
        ys.x += v.x; ys.y += v.y; ys.z += v.z; ys.w += v.w;
    }
    float4 z = *((const float4*)(Z + off));
    float4 o;
    o.x = OMA_F * (0.125f * ys.x) + z.x;
    o.y = OMA_F * (0.125f * ys.y) + z.y;
    o.z = OMA_F * (0.125f * ys.z) + z.z;
    o.w = OMA_F * (0.125f * ys.w) + z.w;

    __syncthreads();            // weights staged
    // stage P tile for the transposed write
    *((float4*)&sm[rl][lane * 4]) = o;

    // ---- fused final_gemm: per-lane partials over this lane's 4 channels
    float a1[6], a2[6];
#pragma unroll
    for (int oo = 0; oo < 6; ++oo) {
        float4 w1 = *((const float4*)&s1[oo * NC + lane * 4]);
        float4 w2 = *((const float4*)&s2[oo * NC + lane * 4]);
        a1[oo] = o.x * w1.x + o.y * w1.y + o.z * w1.z + o.w * w1.w;
        a2[oo] = o.x * w2.x + o.y * w2.y + o.z * w2.z + o.w * w2.w;
    }
    // butterfly over the 32-lane half (masks 1..16 stay within the half)
#pragma unroll
    for (int s = 1; s < 32; s <<= 1) {
#pragma unroll
        for (int oo = 0; oo < 6; ++oo) {
            a1[oo] += __shfl_xor(a1[oo], s);
            a2[oo] += __shfl_xor(a2[oo], s);
        }
    }
    if (lane == 0) {
        float* Ur = U + row * 12;
        float4 u0 = make_float4(a1[0], a1[1], a1[2], a1[3]);
        float4 u1 = make_float4(a1[4], a1[5], a2[0], a2[1]);
        float4 u2 = make_float4(a2[2], a2[3], a2[4], a2[5]);
        *((float4*)(Ur + 0)) = u0;
        *((float4*)(Ur + 4)) = u1;
        *((float4*)(Ur + 8)) = u2;
    }

    __syncthreads();            // sm ready
    // ---- fused transpose: out2[b][c][n0 + 4h .. +3]
    int c = tid >> 1, h = tid & 1;
    float4 v;
    v.x = sm[4 * h + 0][c];
    v.y = sm[4 * h + 1][c];
    v.z = sm[4 * h + 2][c];
    v.w = sm[4 * h + 3][c];
    *((float4*)(out2 + ((size_t)bb * NC + c) * NP + n0 + 4 * h)) = v;
}

// ---------------------------------------------------------------------------
// Final output: new_xyz
// ---------------------------------------------------------------------------
__global__ __launch_bounds__(256) void final_out_kernel(const float* __restrict__ U,
                                                        const int* __restrict__ nbr,
                                                        const float* __restrict__ xyz,
                                                        float* __restrict__ out) {
    size_t row = (size_t)blockIdx.x * 256 + threadIdx.x;
    int b = (int)(row >> 11), n = (int)(row & 2047);
    const int* nb = nbr + row * 7;
    float u1[6], u2[6];
#pragma unroll
    for (int o = 0; o < 6; ++o) { u1[o] = U[row * 12 + o]; u2[o] = U[row * 12 + 6 + o]; }
#pragma unroll
    for (int t = 0; t < 7; ++t) {
        int j = nb[t];
        const float* Uj = U + ((size_t)b * NP + j) * 12 + 6;
#pragma unroll
        for (int o = 0; o < 6; ++o) u2[o] += Uj[o];
    }
#pragma unroll
    for (int c = 0; c < 3; ++c)
#pragma unroll
        for (int s = 0; s < 2; ++s) {
            int o = c * 2 + s;
            float val = ALPHA_F * u1[o] + OMA_F * (0.125f * u2[o])
                      + xyz[(size_t)b * 3 * NP + (size_t)c * NP + n];
            out[(size_t)b * 3 * 2 * NP + (size_t)c * 2 * NP + (size_t)s * NP + n] = val;
        }
}

// ---------------------------------------------------------------------------
extern "C" void kernel_launch(void* const* d_in, const int* in_sizes, int n_in,
                              void* d_out, int out_size, void* d_ws, size_t ws_size,
                              hipStream_t stream) {
    const float* xyz    = (const float*)d_in[0];  // (16,3,2048)
    const float* points = (const float*)d_in[1];  // (16,128,2048)
    const float* Wc     = (const float*)d_in[2];  // (4,128,128)
    const float* Wg     = (const float*)d_in[3];  // (4,128,128)
    const float* Wuc    = (const float*)d_in[4];  // (6,128)
    const float* Wug    = (const float*)d_in[5];  // (6,128)
    float* out = (float*)d_out;

    char* ws = (char*)d_ws;
    size_t o = 0;
    int* nbr  = (int*)(ws + o);     o += (size_t)NB * NP * 7 * 4;
    uint4* WP = (uint4*)(ws + o);   o += (size_t)32768 * 16;           // 0.5 MB
    float* Za = (float*)(ws + o);   o += (size_t)NB * NP * NC * 4;     // 16 MB
    float* Ya = (float*)(ws + o);   o += (size_t)NB * NP * NC * 4;
    float* Zb = (float*)(ws + o);   o += (size_t)NB * NP * NC * 4;
    float* Yb = (float*)(ws + o);   o += (size_t)NB * NP * NC * 4;
    float* U  = (float*)(ws + o);   o += (size_t)NB * NP * 12 * 4;

    const int GEMM_GRID = NB * NP / 64;   // 512 tiles
    // WP slab bases: (layer*2 + mat) * 4096 uint4
    #define WPC(L) (WP + (size_t)((L) * 2 + 0) * 4096)
    #define WPG(L) (WP + (size_t)((L) * 2 + 1) * 4096)

    // 0) pre-split weights (one-time)
    prep_w_kernel<<<64, 256, 0, stream>>>(Wc, Wg, WP);
    // 1) KNN
    knn_kernel<<<dim3(NP / 64, NB), 256, 0, stream>>>(xyz, nbr);
    // 2) GCN blocks — agg fused into next block's A-staging
    gemm_fused_kernel<0><<<GEMM_GRID, 512, 0, stream>>>(points, nullptr, nullptr,
        WPC(0), WPG(0), Za, Ya);
    gemm_fused_kernel<1><<<GEMM_GRID, 512, 0, stream>>>(Za, Ya, nbr,
        WPC(1), WPG(1), Zb, Yb);
    gemm_fused_kernel<1><<<GEMM_GRID, 512, 0, stream>>>(Zb, Yb, nbr,
        WPC(2), WPG(2), Za, Ya);
    gemm_fused_kernel<1><<<GEMM_GRID, 512, 0, stream>>>(Za, Ya, nbr,
        WPC(3), WPG(3), Zb, Yb);
    // 3) fused tail: last agg + final small GEMMs + transpose
    float* out2 = out + (size_t)NB * 3 * 2 * NP;
    agg2_kernel<<<dim3(NB * NP / 8), 256, 0, stream>>>(Zb, Yb, nbr, Wuc, Wug, U, out2);
    // 4) new_xyz
    final_out_kernel<<<dim3(NB * NP / 256), 256, 0, stream>>>(U, nbr, xyz, out);
}

// Round 9
// 197.317 us; speedup vs baseline: 1.1630x; 1.0541x over previous
//
#include <hip/hip_runtime.h>
#include <hip/hip_bf16.h>

// Problem constants
static constexpr int NB = 16;     // batches
static constexpr int NP = 2048;   // points per batch
static constexpr int NC = 128;    // channels
#define ALPHA_F ((float)(8.0/9.0))
#define OMA_F   ((float)(1.0 - 8.0/9.0))

typedef __attribute__((ext_vector_type(8))) short bfrag;   // 8 bf16 (4 VGPR)
typedef __attribute__((ext_vector_type(4))) float ffrag;   // 4 fp32 acc

union BU { bfrag v; uint4 u; unsigned int w[4]; };

// split two floats into packed bf16 hi pair + bf16 lo pair
__device__ inline void split2(float x, float y, unsigned& hi, unsigned& lo) {
    __hip_bfloat162 h = __float22bfloat162_rn(make_float2(x, y));
    float2 hb = __bfloat1622float2(h);
    __hip_bfloat162 l = __float22bfloat162_rn(make_float2(x - hb.x, y - hb.y));
    __builtin_memcpy(&hi, &h, 4);
    __builtin_memcpy(&lo, &l, 4);
}

__device__ inline void split1(float x, unsigned short& h, unsigned short& l) {
    __hip_bfloat16 hb = __float2bfloat16(x);
    float hf = __bfloat162float(hb);
    __hip_bfloat16 lb = __float2bfloat16(x - hf);
    __builtin_memcpy(&h, &hb, 2);
    __builtin_memcpy(&l, &lb, 2);
}

// ---------------------------------------------------------------------------
// KNN v7.1 (unchanged: measured best, ~35us).
// ---------------------------------------------------------------------------
__global__ __launch_bounds__(256) void knn_kernel(const float* __restrict__ xyz,
                                                  int* __restrict__ nbr) {
    __shared__ float4 sp[NP];            // 32 KB (XOR-swizzled slots)
    __shared__ float  md[64][33];
    __shared__ int    mi[64][33];
    int b = blockIdx.y;
    const float* X = xyz + (size_t)b * 3 * NP;
    for (int m = threadIdx.x; m < NP; m += 256) {
        float x = X[m], y = X[NP + m], z = X[2 * NP + m];
        sp[m ^ ((m >> 5) & 7)] = make_float4(x, y, z, x * x + y * y + z * z);
    }
    __syncthreads();

    int tid = threadIdx.x;
    int p = tid >> 2;
    int q = tid & 3;
    int base = blockIdx.x * 64;
    int n = base + p;
    float4 me = sp[n ^ ((n >> 5) & 7)];
    float xi = me.x, yi = me.y, zi = me.z, qi = me.w;

    // ---- pass 1: true group-min for the 16 owned groups (g = q*16 + gg)
    unsigned gd[8];
#pragma unroll
    for (int t = 0; t < 8; ++t) gd[t] = 0x7F7FFFFFu;
#pragma unroll 1
    for (int gg = 0; gg < 16; ++gg) {
        int g = q * 16 + gg;
        const float4* gp = sp + g * 32;     // swizzle permutes within block only
        float m0 = 3.4e38f, m1 = m0, m2 = m0, m3 = m0;
#pragma unroll
        for (int k = 0; k < 32; k += 4) {
            // order-invariant scan, rotated by q so the 4 q-lanes hit
            // 4 distinct bank quads per instruction (k+i^q, i=0..3)
            float4 a0 = gp[(k + 0) ^ q];
            float4 a1 = gp[(k + 1) ^ q];
            float4 a2 = gp[(k + 2) ^ q];
            float4 a3 = gp[(k + 3) ^ q];
            m0 = fminf(m0, qi + a0.w - 2.0f * (xi * a0.x + yi * a0.y + zi * a0.z));
            m1 = fminf(m1, qi + a1.w - 2.0f * (xi * a1.x + yi * a1.y + zi * a1.z));
            m2 = fminf(m2, qi + a2.w - 2.0f * (xi * a2.x + yi * a2.y + zi * a2.z));
            m3 = fminf(m3, qi + a3.w - 2.0f * (xi * a3.x + yi * a3.y + zi * a3.z));
        }
        float gm = fmaxf(fminf(fminf(m0, m1), fminf(m2, m3)), 0.0f);
        unsigned pg; __builtin_memcpy(&pg, &gm, 4);
        pg = (pg & ~63u) | (unsigned)g;      // pack group id in low mantissa
        // sorted-insert via min/max identity (keys unique -> exact)
        unsigned prev = gd[0];
        gd[0] = gd[0] < pg ? gd[0] : pg;
#pragma unroll
        for (int t = 1; t < 8; ++t) {
            unsigned mx = prev > pg ? prev : pg;
            prev = gd[t];
            gd[t] = gd[t] < mx ? gd[t] : mx;
        }
    }

    // ---- cross-lane merge: top-8 of the 4 lanes' 4x8 sorted lists (bitonic)
#define CEU(A, B) { unsigned _lo = (A) < (B) ? (A) : (B); \
                    unsigned _hi = (A) < (B) ? (B) : (A); (A) = _lo; (B) = _hi; }
    unsigned cA[8];
#pragma unroll
    for (int i = 0; i < 8; ++i) {
        unsigned pb = (unsigned)__shfl_xor((int)gd[7 - i], 1);
        cA[i] = gd[i] < pb ? gd[i] : pb;     // 8 smallest of 16 (bitonic half)
    }
    CEU(cA[0], cA[4]); CEU(cA[1], cA[5]); CEU(cA[2], cA[6]); CEU(cA[3], cA[7]);
    CEU(cA[0], cA[2]); CEU(cA[1], cA[3]); CEU(cA[4], cA[6]); CEU(cA[5], cA[7]);
    CEU(cA[0], cA[1]); CEU(cA[2], cA[3]); CEU(cA[4], cA[5]); CEU(cA[6], cA[7]);
    unsigned dA[8];
#pragma unroll
    for (int i = 0; i < 8; ++i) {
        unsigned pb = (unsigned)__shfl_xor((int)cA[7 - i], 2);
        dA[i] = cA[i] < pb ? cA[i] : pb;     // 8 smallest of 32 (all lanes agree)
    }
    unsigned long long mask = 0ull;
#pragma unroll
    for (int i = 0; i < 8; ++i) mask |= (1ull << (dA[i] & 63u));

    // ---- pass 2: full insert over winning groups, ascending group order
    float bd[8]; int bi[8];
#pragma unroll
    for (int t = 0; t < 8; ++t) { bd[t] = 3.4e38f; bi[t] = 0; }
    while (mask) {
        int g = (int)__builtin_ctzll(mask);
        mask &= (mask - 1ull);
        int sw = g & 7;
        int jb = g * 32 + q;
#pragma unroll
        for (int i = 0; i < 8; ++i) {
            int j0 = jb + i * 4;
            float4 c4v = sp[j0 ^ sw];
            float inner = xi * c4v.x + yi * c4v.y + zi * c4v.z;
            float d = qi + c4v.w - 2.0f * inner;
            bool c[8];
#pragma unroll
            for (int t = 0; t < 8; ++t) c[t] = d < bd[t];
#pragma unroll
            for (int t = 7; t >= 1; --t) {
                bd[t] = c[t - 1] ? bd[t - 1] : (c[t] ? d : bd[t]);
                bi[t] = c[t - 1] ? bi[t - 1] : (c[t] ? j0 : bi[t]);
            }
            bd[0] = c[0] ? d : bd[0];
            bi[0] = c[0] ? j0 : bi[0];
        }
    }
#pragma unroll
    for (int t = 0; t < 8; ++t) {
        md[p][q * 8 + t] = bd[t];
        mi[p][q * 8 + t] = bi[t];
    }
    __syncthreads();

    if (tid < 64) {
        float fd[8]; int fi[8];
#pragma unroll
        for (int t = 0; t < 8; ++t) { fd[t] = 3.4e38f; fi[t] = 0; }
#pragma unroll 4
        for (int cc = 0; cc < 32; ++cc) {
            float d = md[tid][cc];
            int j = mi[tid][cc];
            bool c[8];
#pragma unroll
            for (int t = 0; t < 8; ++t) c[t] = d < fd[t];
#pragma unroll
            for (int t = 7; t >= 1; --t) {
                fd[t] = c[t - 1] ? fd[t - 1] : (c[t] ? d : fd[t]);
                fi[t] = c[t - 1] ? fi[t - 1] : (c[t] ? j : fi[t]);
            }
            fd[0] = c[0] ? d : fd[0];
            fi[0] = c[0] ? j : fi[0];
        }
        int row = b * NP + base + tid;
#pragma unroll
        for (int t = 0; t < 7; ++t) nbr[row * 7 + t] = fi[t + 1];
    }
}

// ---------------------------------------------------------------------------
// Pre-split W into MFMA-frag-ordered bf16 hi/lo uint4 pairs (one-time).
// ---------------------------------------------------------------------------
__global__ __launch_bounds__(256) void prep_w_kernel(const float* __restrict__ Wc,
                                                     const float* __restrict__ Wg,
                                                     uint4* __restrict__ WP) {
    int t = blockIdx.x * 256 + threadIdx.x;
    int ncol = t & 127;
    int quad = (t >> 7) & 3;
    int s = (t >> 9) & 3;
    int mat = (t >> 11) & 1;
    int layer = t >> 12;
    const float* W = (mat ? Wg : Wc) + (size_t)layer * NC * NC + (size_t)ncol * NC + s * 32 + quad * 8;
    float4 a = *((const float4*)W);
    float4 b = *((const float4*)(W + 4));
    BU hi, lo;
    split2(a.x, a.y, hi.w[0], lo.w[0]);
    split2(a.z, a.w, hi.w[1], lo.w[1]);
    split2(b.x, b.y, hi.w[2], lo.w[2]);
    split2(b.z, b.w, hi.w[3], lo.w[3]);
    WP[t * 2] = hi.u;
    WP[t * 2 + 1] = lo.u;
}

// ---------------------------------------------------------------------------
// Fused GCN block v4 (round-9): occupancy fix.
// Hypothesis: previous version (no waves/EU bound, 64 VGPRs of W-frags live
// from kernel entry across staging) exceeded 128 VGPR -> 1 block/CU -> the
// 512-block grid ran as two sequential waves with stage/MFMA phases fully
// latency-exposed (~39us/layer vs ~12us of floors).
// Fix: __launch_bounds__(512, 4) (4 waves/SIMD = 16 waves/CU = 2 blocks/CU,
// VGPR <= 128) + W-frag loads moved AFTER the staging barrier so the 64-VGPR
// W lifetime doesn't overlap staging temporaries (no spills under the cap).
// Math identical.
// ---------------------------------------------------------------------------
template <int MODE>
__global__ __launch_bounds__(512, 4) void gemm_fused_kernel(const float* __restrict__ Asrc,
                                                            const float* __restrict__ Y2in,
                                                            const int* __restrict__ nbr,
                                                            const uint4* __restrict__ WPc,
                                                            const uint4* __restrict__ WPg,
                                                            float* __restrict__ Zout,
                                                            float* __restrict__ Y2out) {
    __shared__ unsigned short AhT[64][136];   // 17.4 KB
    __shared__ unsigned short AlT[64][136];   // 17.4 KB
    __shared__ int s_nb[448];
    int tid = threadIdx.x;
    int wid = tid >> 6, lane = tid & 63;
    int quad = lane >> 4, l15 = lane & 15;
    int xcd = blockIdx.x & 7;
    int slot = blockIdx.x >> 3;
    int bb = xcd * 2 + (slot >> 5);           // batch
    int n0 = (slot & 31) << 6;                // tile base within batch
    size_t m0 = (size_t)bb * NP + n0;
    int ncol = wid * 16 + l15;

    // ---- stage A tile, splitting to bf16 planes inline
    if (MODE == 1) {
        if (tid < 448) s_nb[tid] = nbr[m0 * 7 + tid];
        __syncthreads();
        size_t bbase = (size_t)bb * NP;
#pragma unroll 1
        for (int it = 0; it < 4; ++it) {
            int f = tid + it * 512;
            int r = f >> 5, c4 = (f & 31) * 4;
            size_t row = m0 + r;
            float4 z = *((const float4*)(Asrc + row * NC + c4));
            float4 acc = *((const float4*)(Y2in + row * NC + c4));
#pragma unroll
            for (int t = 0; t < 7; ++t) {
                int j = s_nb[r * 7 + t];
                float4 v = *((const float4*)(Y2in + (bbase + (size_t)j) * NC + c4));
                acc.x += v.x; acc.y += v.y; acc.z += v.z; acc.w += v.w;
            }
            float4 a;
            a.x = OMA_F * (0.125f * acc.x) + z.x;
            a.y = OMA_F * (0.125f * acc.y) + z.y;
            a.z = OMA_F * (0.125f * acc.z) + z.z;
            a.w = OMA_F * (0.125f * acc.w) + z.w;
            unsigned h01, l01, h23, l23;
            split2(a.x, a.y, h01, l01);
            split2(a.z, a.w, h23, l23);
            *((uint2*)&AhT[r][c4]) = make_uint2(h01, h23);
            *((uint2*)&AlT[r][c4]) = make_uint2(l01, l23);
        }
    } else {
        // A[r][c] = points[b][c][n0+r]: float4 along n, split scalar, b16 writes
#pragma unroll
        for (int it = 0; it < 4; ++it) {
            int f = tid + it * 512;
            int c = f >> 4, rq = (f & 15) * 4;
            float4 v = *((const float4*)(Asrc + ((size_t)bb * NC + c) * NP + n0 + rq));
            float vv[4] = {v.x, v.y, v.z, v.w};
#pragma unroll
            for (int k = 0; k < 4; ++k) {
                unsigned short h, l;
                split1(vv[k], h, l);
                AhT[rq + k][c] = h;
                AlT[rq + k][c] = l;
            }
        }
    }
    __syncthreads();

    // ---- W frags AFTER staging: pre-split, frag-ordered, L2-hot b128 loads.
    // Loaded here so their 64 VGPRs don't overlap the staging working set.
    BU Bch[4], Bcl[4], Bgh[4], Bgl[4];
#pragma unroll
    for (int s = 0; s < 4; ++s) {
        int idx = ((s * 4 + quad) * 128 + ncol) * 2;
        Bch[s].u = WPc[idx];
        Bcl[s].u = WPc[idx + 1];
        Bgh[s].u = WPg[idx];
        Bgl[s].u = WPg[idx + 1];
    }

    ffrag accC[4], accG[4];
#pragma unroll
    for (int mt = 0; mt < 4; ++mt) { accC[mt] = (ffrag)0.0f; accG[mt] = (ffrag)0.0f; }

#pragma unroll
    for (int s = 0; s < 4; ++s) {
#pragma unroll
        for (int mt = 0; mt < 4; ++mt) {
            int m = mt * 16 + l15;
            int k = s * 32 + quad * 8;
            BU ah, al, rh, rl;
            ah.u = *((const uint4*)&AhT[m][k]);
            al.u = *((const uint4*)&AlT[m][k]);
#pragma unroll
            for (int w = 0; w < 4; ++w) {
                unsigned msk = ((ah.w[w] & 0x80008000u) >> 15) * 0xFFFFu;
                rh.w[w] = ah.w[w] & ~msk;
                rl.w[w] = al.w[w] & ~msk;
            }
            accC[mt] = __builtin_amdgcn_mfma_f32_16x16x32_bf16(rh.v, Bch[s].v, accC[mt], 0, 0, 0);
            accC[mt] = __builtin_amdgcn_mfma_f32_16x16x32_bf16(rh.v, Bcl[s].v, accC[mt], 0, 0, 0);
            accC[mt] = __builtin_amdgcn_mfma_f32_16x16x32_bf16(rl.v, Bch[s].v, accC[mt], 0, 0, 0);
            accG[mt] = __builtin_amdgcn_mfma_f32_16x16x32_bf16(ah.v, Bgh[s].v, accG[mt], 0, 0, 0);
            accG[mt] = __builtin_amdgcn_mfma_f32_16x16x32_bf16(ah.v, Bgl[s].v, accG[mt], 0, 0, 0);
            accG[mt] = __builtin_amdgcn_mfma_f32_16x16x32_bf16(al.v, Bgh[s].v, accG[mt], 0, 0, 0);
        }
    }

    // ---- epilogue: col = l15, row = 4*quad + r; residual p = hi + lo
#pragma unroll
    for (int mt = 0; mt < 4; ++mt) {
        int rbase = mt * 16 + quad * 4;
#pragma unroll
        for (int r = 0; r < 4; ++r) {
            int rr = rbase + r;
            unsigned hb = ((unsigned)AhT[rr][ncol]) << 16;
            unsigned lb = ((unsigned)AlT[rr][ncol]) << 16;
            float hp, lp;
            __builtin_memcpy(&hp, &hb, 4);
            __builtin_memcpy(&lp, &lb, 4);
            float p = hp + lp;
            size_t idx = (m0 + rr) * NC + ncol;
            Zout[idx] = p + ALPHA_F * accC[mt][r];
            Y2out[idx] = accG[mt][r];
        }
    }
}

// ---------------------------------------------------------------------------
// agg2 (unchanged): fused tail = agg + final_gemm + transpose.
// ---------------------------------------------------------------------------
__global__ __launch_bounds__(256) void agg2_kernel(const float* __restrict__ Z,
                                                   const float* __restrict__ Y2,
                                                   const int* __restrict__ nbr,
                                                   const float* __restrict__ Wuc,
                                                   const float* __restrict__ Wug,
                                                   float* __restrict__ U,
                                                   float* __restrict__ out2) {
    __shared__ float s1[6 * NC], s2[6 * NC];   // 6 KB weights
    __shared__ float sm[8][132];               // 4.2 KB P tile (padded)
    int tid = threadIdx.x;
    int lane = tid & 31, rl = tid >> 5;
    for (int m = tid; m < 6 * NC; m += 256) { s1[m] = Wuc[m]; s2[m] = Wug[m]; }

    int xcd = blockIdx.x & 7;
    int slot = blockIdx.x >> 3;
    int bb = xcd * 2 + (slot >> 8);
    int rblk = slot & 255;
    int n0 = rblk * 8;
    size_t row = ((size_t)bb << 11) + n0 + rl;
    const int* nb = nbr + row * 7;
    size_t off = row * NC + lane * 4;
    float4 ys = *((const float4*)(Y2 + off));
    size_t bbase = (size_t)bb * NP * NC;
#pragma unroll
    for (int t = 0; t < 7; ++t) {
        int j = nb[t];
        float4 v = *((const float4*)(Y2 + bbase + (size_t)j * NC + lane * 4));
        ys.x += v.x; ys.y += v.y; ys.z += v.z; ys.w += v.w;
    }
    float4 z = *((const float4*)(Z + off));
    float4 o;
    o.x = OMA_F * (0.125f * ys.x) + z.x;
    o.y = OMA_F * (0.125f * ys.y) + z.y;
    o.z = OMA_F * (0.125f * ys.z) + z.z;
    o.w = OMA_F * (0.125f * ys.w) + z.w;

    __syncthreads();            // weights staged
    // stage P tile for the transposed write
    *((float4*)&sm[rl][lane * 4]) = o;

    // ---- fused final_gemm: per-lane partials over this lane's 4 channels
    float a1[6], a2[6];
#pragma unroll
    for (int oo = 0; oo < 6; ++oo) {
        float4 w1 = *((const float4*)&s1[oo * NC + lane * 4]);
        float4 w2 = *((const float4*)&s2[oo * NC + lane * 4]);
        a1[oo] = o.x * w1.x + o.y * w1.y + o.z * w1.z + o.w * w1.w;
        a2[oo] = o.x * w2.x + o.y * w2.y + o.z * w2.z + o.w * w2.w;
    }
    // butterfly over the 32-lane half (masks 1..16 stay within the half)
#pragma unroll
    for (int s = 1; s < 32; s <<= 1) {
#pragma unroll
        for (int oo = 0; oo < 6; ++oo) {
            a1[oo] += __shfl_xor(a1[oo], s);
            a2[oo] += __shfl_xor(a2[oo], s);
        }
    }
    if (lane == 0) {
        float* Ur = U + row * 12;
        float4 u0 = make_float4(a1[0], a1[1], a1[2], a1[3]);
        float4 u1 = make_float4(a1[4], a1[5], a2[0], a2[1]);
        float4 u2 = make_float4(a2[2], a2[3], a2[4], a2[5]);
        *((float4*)(Ur + 0)) = u0;
        *((float4*)(Ur + 4)) = u1;
        *((float4*)(Ur + 8)) = u2;
    }

    __syncthreads();            // sm ready
    // ---- fused transpose: out2[b][c][n0 + 4h .. +3]
    int c = tid >> 1, h = tid & 1;
    float4 v;
    v.x = sm[4 * h + 0][c];
    v.y = sm[4 * h + 1][c];
    v.z = sm[4 * h + 2][c];
    v.w = sm[4 * h + 3][c];
    *((float4*)(out2 + ((size_t)bb * NC + c) * NP + n0 + 4 * h)) = v;
}

// ---------------------------------------------------------------------------
// Final output: new_xyz
// ---------------------------------------------------------------------------
__global__ __launch_bounds__(256) void final_out_kernel(const float* __restrict__ U,
                                                        const int* __restrict__ nbr,
                                                        const float* __restrict__ xyz,
                                                        float* __restrict__ out) {
    size_t row = (size_t)blockIdx.x * 256 + threadIdx.x;
    int b = (int)(row >> 11), n = (int)(row & 2047);
    const int* nb = nbr + row * 7;
    float u1[6], u2[6];
#pragma unroll
    for (int o = 0; o < 6; ++o) { u1[o] = U[row * 12 + o]; u2[o] = U[row * 12 + 6 + o]; }
#pragma unroll
    for (int t = 0; t < 7; ++t) {
        int j = nb[t];
        const float* Uj = U + ((size_t)b * NP + j) * 12 + 6;
#pragma unroll
        for (int o = 0; o < 6; ++o) u2[o] += Uj[o];
    }
#pragma unroll
    for (int c = 0; c < 3; ++c)
#pragma unroll
        for (int s = 0; s < 2; ++s) {
            int o = c * 2 + s;
            float val = ALPHA_F * u1[o] + OMA_F * (0.125f * u2[o])
                      + xyz[(size_t)b * 3 * NP + (size_t)c * NP + n];
            out[(size_t)b * 3 * 2 * NP + (size_t)c * 2 * NP + (size_t)s * NP + n] = val;
        }
}

// ---------------------------------------------------------------------------
extern "C" void kernel_launch(void* const* d_in, const int* in_sizes, int n_in,
                              void* d_out, int out_size, void* d_ws, size_t ws_size,
                              hipStream_t stream) {
    const float* xyz    = (const float*)d_in[0];  // (16,3,2048)
    const float* points = (const float*)d_in[1];  // (16,128,2048)
    const float* Wc     = (const float*)d_in[2];  // (4,128,128)
    const float* Wg     = (const float*)d_in[3];  // (4,128,128)
    const float* Wuc    = (const float*)d_in[4];  // (6,128)
    const float* Wug    = (const float*)d_in[5];  // (6,128)
    float* out = (float*)d_out;

    char* ws = (char*)d_ws;
    size_t o = 0;
    int* nbr  = (int*)(ws + o);     o += (size_t)NB * NP * 7 * 4;
    uint4* WP = (uint4*)(ws + o);   o += (size_t)32768 * 16;           // 0.5 MB
    float* Za = (float*)(ws + o);   o += (size_t)NB * NP * NC * 4;     // 16 MB
    float* Ya = (float*)(ws + o);   o += (size_t)NB * NP * NC * 4;
    float* Zb = (float*)(ws + o);   o += (size_t)NB * NP * NC * 4;
    float* Yb = (float*)(ws + o);   o += (size_t)NB * NP * NC * 4;
    float* U  = (float*)(ws + o);   o += (size_t)NB * NP * 12 * 4;

    const int GEMM_GRID = NB * NP / 64;   // 512 tiles
    // WP slab bases: (layer*2 + mat) * 4096 uint4
    #define WPC(L) (WP + (size_t)((L) * 2 + 0) * 4096)
    #define WPG(L) (WP + (size_t)((L) * 2 + 1) * 4096)

    // 0) pre-split weights (one-time)
    prep_w_kernel<<<64, 256, 0, stream>>>(Wc, Wg, WP);
    // 1) KNN
    knn_kernel<<<dim3(NP / 64, NB), 256, 0, stream>>>(xyz, nbr);
    // 2) GCN blocks — agg fused into next block's A-staging
    gemm_fused_kernel<0><<<GEMM_GRID, 512, 0, stream>>>(points, nullptr, nullptr,
        WPC(0), WPG(0), Za, Ya);
    gemm_fused_kernel<1><<<GEMM_GRID, 512, 0, stream>>>(Za, Ya, nbr,
        WPC(1), WPG(1), Zb, Yb);
    gemm_fused_kernel<1><<<GEMM_GRID, 512, 0, stream>>>(Zb, Yb, nbr,
        WPC(2), WPG(2), Za, Ya);
    gemm_fused_kernel<1><<<GEMM_GRID, 512, 0, stream>>>(Za, Ya, nbr,
        WPC(3), WPG(3), Zb, Yb);
    // 3) fused tail: last agg + final small GEMMs + transpose
    float* out2 = out + (size_t)NB * 3 * 2 * NP;
    agg2_kernel<<<dim3(NB * NP / 8), 256, 0, stream>>>(Zb, Yb, nbr, Wuc, Wug, U, out2);
    // 4) new_xyz
    final_out_kernel<<<dim3(NB * NP / 256), 256, 0, stream>>>(U, nbr, xyz, out);
}